// Round 11
// baseline (245.239 us; speedup 1.0000x reference)
//
#include <hip/hip_runtime.h>

typedef unsigned short u16;
typedef unsigned int   u32;
typedef float f32x4 __attribute__((ext_vector_type(4)));
typedef __bf16 bf16x8 __attribute__((ext_vector_type(8)));
typedef unsigned short u16x8 __attribute__((ext_vector_type(8)));
typedef unsigned short u16x4 __attribute__((ext_vector_type(4)));

#define PP   6400
#define HH   80
#define WW   80
#define KC   256
#define CH   324
#define CPAD 384
#define PW   82          // padded spatial width
#define PPIX (PW*PW)     // 6724 padded pixels
#define NP2  896         // per-m-tile pooled cols: L1 12 rows (480) + L2 12 rows (240) + L3 (100) + pad

__device__ inline float b2f(u16 u) { union { u32 i; float f; } v; v.i = ((u32)u) << 16; return v.f; }
__device__ inline u16 f2b(float f) {
    union { u32 i; float f; } v; v.f = f;
    u32 r = v.i + 0x7fffu + ((v.i >> 16) & 1u);
    return (u16)(r >> 16);
}

// async global->LDS, 16B per lane; LDS dst = wave-uniform base + lane*16
__device__ __forceinline__ void gload16(const void* g, void* l) {
    __builtin_amdgcn_global_load_lds((const __attribute__((address_space(1))) void*)g,
                                     (__attribute__((address_space(3))) void*)l, 16, 0, 0);
}

// ---------------- prep_all: feature transpose (blocks 0..799) + weight transpose (800..1447) ----------------
__global__ __launch_bounds__(256) void prep_all(const float* __restrict__ f0,
                                                const float* __restrict__ f1,
                                                u16* __restrict__ fA, u16* __restrict__ fB,
                                                const float* __restrict__ w1,
                                                const float* __restrict__ w2,
                                                u16* __restrict__ wT1, u16* __restrict__ wT2) {
    __shared__ float tile[64][65];
    int bid = (int)blockIdx.x;
    int tid = threadIdx.x;
    if (bid < 800) {
        int x = bid % 100, yb = (bid / 100) % 4, z = bid / 400;
        int p0 = x * 64, c0 = yb * 64;
        const float* src = z ? f1 : f0;
        u16* dst = z ? fB : fA;
#pragma unroll
        for (int it = 0; it < 4; ++it) {
            int idx = tid + it * 256;                 // 0..1023
            int cc = idx >> 4, pp4 = (idx & 15) * 4;
            f32x4 v = *(const f32x4*)(&src[(size_t)(c0 + cc) * PP + p0 + pp4]);
            tile[cc][pp4]     = v[0];
            tile[cc][pp4 + 1] = v[1];
            tile[cc][pp4 + 2] = v[2];
            tile[cc][pp4 + 3] = v[3];
        }
        __syncthreads();
#pragma unroll
        for (int it = 0; it < 4; ++it) {
            int idx = tid + it * 256;
            int pp = idx >> 4, cc4 = (idx & 15) * 4;
            u16x4 o;
            o[0] = f2b(tile[cc4][pp]);
            o[1] = f2b(tile[cc4 + 1][pp]);
            o[2] = f2b(tile[cc4 + 2][pp]);
            o[3] = f2b(tile[cc4 + 3][pp]);
            *(u16x4*)(&dst[(size_t)(p0 + pp) * KC + c0 + cc4]) = o;
        }
    } else {
        int b = bid - 800;
        int tap = b % 9, t6 = (b / 9) % 36, z = b / 324;
        int ci0 = (t6 / 6) * 64, co0 = (t6 % 6) * 64;
        const float* w = z ? w2 : w1;
        u16* wT = z ? wT2 : wT1;
#pragma unroll
        for (int it = 0; it < 16; ++it) {
            int idx = tid + it * 256;
            int ciL = idx >> 6, coL = idx & 63;
            int ci = ci0 + ciL, co = co0 + coL;
            tile[ciL][coL] = (ci < CH && co < CH) ? w[((size_t)tap * CH + ci) * CH + co] : 0.f;
        }
        __syncthreads();
#pragma unroll
        for (int it = 0; it < 16; ++it) {
            int idx = tid + it * 256;
            int coL = idx >> 6, ciL = idx & 63;
            wT[((size_t)tap * CPAD + co0 + coL) * CPAD + ci0 + ciL] = f2b(tile[ciL][coL]);
        }
    }
}

// ---------------- zpool: halo-zero + bias prep (blocks 0..649) + pooled features (650..849) ----------------
__global__ __launch_bounds__(384) void zpool(u16* __restrict__ feat, u16* __restrict__ t1,
                                             const float* __restrict__ b1,
                                             const float* __restrict__ b2,
                                             float* __restrict__ b1p, float* __restrict__ b2p,
                                             const u16* __restrict__ fA, const u16* __restrict__ fB,
                                             u16* __restrict__ pbarA, u16* __restrict__ pbarB) {
    int bid = (int)blockIdx.x;
    int t = threadIdx.x;
    if (bid < 650) {
        int bi = bid % 325, dir = bid / 325;
        if (bi == 324) {                              // bias-prep block
            if (dir == 0) b1p[t] = t < CH ? b1[t] : 0.f;
            else          b2p[t] = t < CH ? b2[t] : 0.f;
            return;
        }
        int pix;
        if (bi < 82) pix = bi;                        // top row
        else if (bi < 164) pix = 81 * PW + (bi - 82); // bottom row
        else if (bi < 244) pix = (bi - 164 + 1) * PW; // left col
        else pix = (bi - 244 + 1) * PW + 81;          // right col
        size_t off = ((size_t)dir * PPIX + pix) * CPAD + t;
        feat[off] = 0;
        t1[off] = 0;
        return;
    }
    if (t >= 256) return;
    int b = bid - 650;
    int j = b % 100, yy = b / 100;
    const u16* src = yy ? fA : fB;
    u16* dst = yy ? pbarA : pbarB;
    int k = t;
    int cy3 = j / 10, cx3 = j % 10;
    float l1v[16], l2v[4];
#pragma unroll
    for (int a = 0; a < 4; ++a)
#pragma unroll
        for (int bb = 0; bb < 4; ++bb) {
            int cy = cy3 * 4 + a, cx = cx3 * 4 + bb;
            int p00 = (2 * cy) * 80 + 2 * cx;
            float v = 0.25f * (b2f(src[(size_t)p00 * KC + k]) + b2f(src[(size_t)(p00 + 1) * KC + k]) +
                               b2f(src[(size_t)(p00 + 80) * KC + k]) + b2f(src[(size_t)(p00 + 81) * KC + k]));
            l1v[a * 4 + bb] = v;
            dst[(size_t)(cy * 40 + cx) * KC + k] = f2b(v);
        }
#pragma unroll
    for (int a = 0; a < 2; ++a)
#pragma unroll
        for (int bb = 0; bb < 2; ++bb) {
            float v = 0.25f * (l1v[(2 * a) * 4 + 2 * bb] + l1v[(2 * a) * 4 + 2 * bb + 1] +
                               l1v[(2 * a + 1) * 4 + 2 * bb] + l1v[(2 * a + 1) * 4 + 2 * bb + 1]);
            l2v[a * 2 + bb] = v;
            dst[(size_t)(1600 + (cy3 * 2 + a) * 20 + cx3 * 2 + bb) * KC + k] = f2b(v);
        }
    float v3 = 0.25f * (l2v[0] + l2v[1] + l2v[2] + l2v[3]);
    dst[(size_t)(2000 + j) * KC + k] = f2b(v3);
}

// ---------------- merged GEMM: banded corr (y<7) + windowed pooled-corr (y=7..20) ----------------
// R11: BK=128, 2 K-steps (drain pairs 4->2, 64 MFMA/wave/step), 64KB LDS -> 2 blocks/CU
// (demand 4.1/CU so 2 stay resident; inter-block interleave retained). K-chunk order
// unchanged -> bit-identical accumulation. 16-chunk XOR swizzle = conv_gemm's proven scheme.
__global__ __launch_bounds__(256) void gemm_cp(const u16* __restrict__ fA,
                                               const u16* __restrict__ fB,
                                               const u16* __restrict__ pbarA,
                                               const u16* __restrict__ pbarB,
                                               u16* __restrict__ pc,
                                               u16* __restrict__ feat) {
    int y = blockIdx.y;
    bool band = (y < 7);
    int m0 = blockIdx.x * 128, n0 = 0, jbase = 0, dir = 0;
    const u16 *Aptr, *Bptr;
    if (band) {
        int n0t = (int)blockIdx.x + y - 3;
        if (n0t < 0 || n0t >= 50) return;
        n0 = n0t * 128;
        Aptr = fA; Bptr = fB;
    } else {
        int q = y - 7;
        dir = q / 7;
        jbase = (q % 7) * 128;
        Aptr = dir ? fB : fA;
        Bptr = dir ? pbarA : pbarB;
    }
    int py0 = m0 / 80;
    int s1 = min(max(py0 / 2 - 5, 0), 28);
    int s2 = min(max(py0 / 4 - 5, 0), 8);

    __shared__ __align__(16) char smem[65536];      // As(32K)+Bs(32K); trans(34K) overlaps
    u16* As = (u16*)smem;
    u16* Bs = As + 128 * 128;
    u16* trans = (u16*)smem;
    const int TS = 136;
    int tid = threadIdx.x;
    int wave = tid >> 6, lane = tid & 63;
    int quad = lane >> 4, l16 = lane & 15;
    int wr = (wave >> 1) * 64, wc = (wave & 1) * 64;
    f32x4 acc[4][4] = {};

    // per-lane staged rows (8 loads each for A and B per K-step); 16-chunk XOR swizzle
    int aRow[8], scW[8];
    size_t gRow[8];
#pragma unroll
    for (int i = 0; i < 8; ++i) {
        int row = wave * 32 + i * 4 + quad;
        aRow[i] = m0 + row;
        scW[i] = l16 ^ (row & 15);
        if (band) gRow[i] = (size_t)(n0 + row);
        else {
            int j = jbase + row;
            int g = j < 480 ? s1 * 40 + j
                  : j < 720 ? 1120 + s2 * 20 + j
                  : j < 820 ? 1280 + j
                  : 2099;
            gRow[i] = (size_t)g;
        }
    }

#pragma unroll
    for (int k0 = 0; k0 < 2; ++k0) {
        int kc = k0 * 128;
        __syncthreads();
#pragma unroll
        for (int i = 0; i < 8; ++i)
            gload16(&Aptr[(size_t)aRow[i] * KC + kc + scW[i] * 8], &As[(wave * 32 + i * 4) * 128]);
#pragma unroll
        for (int j = 0; j < 8; ++j)
            gload16(&Bptr[gRow[j] * KC + kc + scW[j] * 8], &Bs[(wave * 32 + j * 4) * 128]);
        __syncthreads();
#pragma unroll
        for (int ki = 0; ki < 4; ++ki) {
            int slot = (ki * 4 + quad) ^ l16;
            bf16x8 af[4], bfr[4];
#pragma unroll
            for (int mi = 0; mi < 4; ++mi)
                af[mi] = *(const bf16x8*)(&As[(wr + mi * 16 + l16) * 128 + slot * 8]);
#pragma unroll
            for (int ni = 0; ni < 4; ++ni)
                bfr[ni] = *(const bf16x8*)(&Bs[(wc + ni * 16 + l16) * 128 + slot * 8]);
#pragma unroll
            for (int mi = 0; mi < 4; ++mi)
#pragma unroll
                for (int ni = 0; ni < 4; ++ni)
                    acc[mi][ni] = __builtin_amdgcn_mfma_f32_16x16x32_bf16(af[mi], bfr[ni], acc[mi][ni], 0, 0, 0);
        }
    }
    if (band) {
        // direct scatter of valid L0 entries to feat, both directions (R8 mapping)
        u16* fd0 = feat;
        u16* fd1 = feat + (size_t)PPIX * CPAD;
#pragma unroll
        for (int ni = 0; ni < 4; ++ni) {
            int q = n0 + wc + ni * 16 + l16;
            int qy = q / 80, qx = q - qy * 80;
            size_t qpix = (size_t)((qy + 1) * PW + qx + 1) * CPAD;
#pragma unroll
            for (int mi = 0; mi < 4; ++mi)
#pragma unroll
                for (int rr = 0; rr < 4; ++rr) {
                    int p = m0 + wr + mi * 16 + quad * 4 + rr;
                    int py = p / 80, px = p - py * 80;
                    int dx = qx - px, dy = qy - py;
                    if ((unsigned)(dx + 4) < 9u && (unsigned)(dy + 4) < 9u) {
                        u16 v = f2b(acc[mi][ni][rr]);
                        size_t ppix = (size_t)((py + 1) * PW + px + 1) * CPAD;
                        fd0[ppix + (dx + 4) * 9 + (dy + 4)] = v;
                        fd1[qpix + (4 - dx) * 9 + (4 - dy)] = v;
                    }
                }
        }
        return;
    }
    // pooled: stage tile row-major into LDS, write 256B-contiguous rows
    __syncthreads();
#pragma unroll
    for (int mi = 0; mi < 4; ++mi)
#pragma unroll
        for (int ni = 0; ni < 4; ++ni) {
            int rbase = wr + mi * 16 + quad * 4;
            int c = wc + ni * 16 + l16;
#pragma unroll
            for (int rr = 0; rr < 4; ++rr)
                trans[(rbase + rr) * TS + c] = f2b(acc[mi][ni][rr]);
        }
    __syncthreads();
#pragma unroll
    for (int it = 0; it < 8; ++it) {
        int r = it * 16 + (tid >> 4);
        int c8 = (tid & 15) * 8;
        u16x8 v = *(const u16x8*)(&trans[r * TS + c8]);
        *(u16x8*)(&pc[((size_t)dir * PP + m0 + r) * NP2 + jbase + c8]) = v;
    }
}

// ---------------- lookup: 4 pixels per block; windowed pooled rows (L1-3) + L0 zero-fill ----------------
__global__ __launch_bounds__(384) void lookup(const u16* __restrict__ pc,
                                              u16* __restrict__ feat) {
    __shared__ __align__(16) u16 pcrow[4][NP2];     // 7.2 KB
    int p0 = blockIdx.x * 4, dir = blockIdx.y;
    int tid = threadIdx.x;
    int mt = p0 >> 7;
    int py0 = (mt * 128) / 80;
    int s1 = min(max(py0 / 2 - 5, 0), 28);
    int s2 = min(max(py0 / 4 - 5, 0), 8);
    for (int i = tid; i < 4 * (NP2 / 8); i += 384) {
        int j = i / (NP2 / 8), cc = i % (NP2 / 8);
        *(u16x8*)(&pcrow[j][cc * 8]) =
            *(const u16x8*)(&pc[((size_t)dir * PP + p0 + j) * NP2 + cc * 8]);
    }
    __syncthreads();
    int ch = tid;
#pragma unroll
    for (int j = 0; j < 4; ++j) {
        int p = p0 + j;
        int px = p % WW, py = p / WW;
        size_t pix = (size_t)(py + 1) * PW + px + 1;
        if (ch < 81) {
            int dx = ch / 9 - 4, dy = ch % 9 - 4;
            int x = px + dx, yy = py + dy;
            if ((unsigned)x >= (unsigned)WW || (unsigned)yy >= (unsigned)HH)
                feat[((size_t)dir * PPIX + pix) * CPAD + ch] = 0;
            // else: already written by gemm_cp band scatter
        } else if (ch < CH) {
            int lvl = ch / 81, i = ch % 81;
            int dx = i / 9 - 4, dy = i % 9 - 4;
            int wl = WW >> lvl;
            float inv = 1.0f / (float)(2 << lvl);
            float xc = (float)(2 * px + 1) * inv - 0.5f + (float)dx;
            float yc = (float)(2 * py + 1) * inv - 0.5f + (float)dy;
            float x0f = floorf(xc), y0f = floorf(yc);
            int x0 = (int)x0f, y0 = (int)y0f;
            float wx = xc - x0f, wy = yc - y0f;
            float val = 0.f;
#pragma unroll
            for (int cy = 0; cy < 2; ++cy)
#pragma unroll
                for (int cx = 0; cx < 2; ++cx) {
                    int xi = x0 + cx, yi = y0 + cy;
                    if ((unsigned)xi < (unsigned)wl && (unsigned)yi < (unsigned)wl) {
                        float wgt = (cx ? wx : 1.f - wx) * (cy ? wy : 1.f - wy);
                        int idx = (lvl == 1) ? (yi - s1) * 40 + xi
                                : (lvl == 2) ? 480 + (yi - s2) * 20 + xi
                                             : 720 + yi * 10 + xi;
                        val += b2f(pcrow[j][idx]) * wgt;
                    }
                }
            feat[((size_t)dir * PPIX + pix) * CPAD + ch] = f2b(val);
        } else {
            feat[((size_t)dir * PPIX + pix) * CPAD + ch] = 0;
        }
    }
}

// ---------------- conv GEMM: R0/R5 proven structure (64x128 tile, BK=128, 624 blocks, ~57us) ----------------
// Structural plateau for this shape (R2/R3/R6/R9 regressed or flat): MfmaUtil pinned ~23% by
// {load-issue -> vmcnt(0) drain -> barrier -> 160cy MFMA}; any larger tile cuts grid < 2 blocks/CU.
__global__ __launch_bounds__(256) void conv_gemm(const u16* __restrict__ inFeat,
                                                 const u16* __restrict__ wTt,
                                                 const float* __restrict__ bias,
                                                 const u16* __restrict__ resid,
                                                 u16* __restrict__ outb) {
    int L = (int)blockIdx.x;
    int xcd = L & 7;
    int q = L >> 3;
    int n_t = q % 3; q /= 3;
    int mg = q % 13;
    int dir = q / 13;
    int m_t = mg * 8 + xcd;
    if (m_t >= 100) return;
    const u16* Ain = inFeat + (size_t)dir * PPIX * CPAD;
    const u16* Rin = resid ? resid + (size_t)dir * PPIX * CPAD : (const u16*)0;
    u16* Out = outb + (size_t)dir * PPIX * CPAD;
    __shared__ __align__(16) u16 As[64 * 128];    // 16KB
    __shared__ __align__(16) u16 Bs[128 * 128];   // 32KB
    int tid = threadIdx.x;
    int wave = tid >> 6, lane = tid & 63;
    int quad = lane >> 4, l16 = lane & 15;
    int wr = (wave >> 1) * 32, wc = (wave & 1) * 64;
    int m0 = m_t * 64, n0 = n_t * 128;
    f32x4 acc[2][4] = {};

    int pixA[4], scI[4];
#pragma unroll
    for (int i = 0; i < 4; ++i) {
        int r = wave * 16 + i * 4 + quad;
        int m = m0 + r;
        pixA[i] = (m / 80 + 1) * PW + (m % 80) + 1;
        scI[i] = l16 ^ ((i * 4 + quad) & 15);
    }

    for (int tap = 0; tap < 9; ++tap) {
        int dpix = (tap / 3 - 1) * PW + (tap % 3) - 1;
        const u16* Wt = wTt + ((size_t)tap * CPAD + n0) * CPAD;
#pragma unroll
        for (int kt = 0; kt < 3; ++kt) {
            int kc = kt * 128;
            __syncthreads();
#pragma unroll
            for (int i = 0; i < 4; ++i)
                gload16(&Ain[(size_t)(pixA[i] + dpix) * CPAD + kc + scI[i] * 8],
                        &As[(wave * 16 + i * 4) * 128]);
#pragma unroll
            for (int j = 0; j < 8; ++j) {
                int rb = wave * 32 + j * 4;
                gload16(&Wt[(size_t)(rb + quad) * CPAD + kc + scI[j & 3] * 8],
                        &Bs[rb * 128]);
            }
            __syncthreads();
#pragma unroll
            for (int ki = 0; ki < 4; ++ki) {
                int slot = (ki * 4 + quad) ^ l16;
                bf16x8 af[2], bfr[4];
#pragma unroll
                for (int mi = 0; mi < 2; ++mi)
                    af[mi] = *(const bf16x8*)(&As[(wr + mi * 16 + l16) * 128 + slot * 8]);
#pragma unroll
                for (int ni = 0; ni < 4; ++ni)
                    bfr[ni] = *(const bf16x8*)(&Bs[(wc + ni * 16 + l16) * 128 + slot * 8]);
#pragma unroll
                for (int mi = 0; mi < 2; ++mi)
#pragma unroll
                    for (int ni = 0; ni < 4; ++ni)
                        acc[mi][ni] = __builtin_amdgcn_mfma_f32_16x16x32_bf16(af[mi], bfr[ni], acc[mi][ni], 0, 0, 0);
            }
        }
    }
#pragma unroll
    for (int mi = 0; mi < 2; ++mi)
#pragma unroll
        for (int rr = 0; rr < 4; ++rr) {
            int p = m0 + wr + mi * 16 + quad * 4 + rr;
            size_t opix = (size_t)(p / 80 + 1) * PW + (p % 80) + 1;
#pragma unroll
            for (int ni = 0; ni < 4; ++ni) {
                int co = n0 + wc + ni * 16 + l16;
                float v = acc[mi][ni][rr] + bias[co];
                v = fmaxf(v, 0.f);
                if (Rin) v += b2f(Rin[opix * CPAD + co]);
                Out[opix * CPAD + co] = f2b(v);
            }
        }
}

// ---------------- layernorm + transposed (channel-major) output (u16x8 loads) ----------------
__global__ __launch_bounds__(256) void ln_out(const u16* __restrict__ t2,
                                              const float* __restrict__ g,
                                              const float* __restrict__ b,
                                              float* __restrict__ out) {
    int dir = blockIdx.y;
    int p0 = blockIdx.x * 64;
    const u16* Y = t2 + (size_t)dir * PPIX * CPAD;
    __shared__ u16 buf[64 * 325];
    __shared__ float mean_s[64], inv_s[64];
    __shared__ float part[64][4][2];
    int tid = threadIdx.x;
    for (int ci = tid; ci < 64 * 40; ci += 256) {
        int pp = ci / 40, c8 = (ci - pp * 40) * 8;
        int p = p0 + pp;
        size_t pix = (size_t)(p / 80 + 1) * PW + (p % 80) + 1;
        u16x8 v = *(const u16x8*)(&Y[pix * CPAD + c8]);
#pragma unroll
        for (int k = 0; k < 8; ++k) buf[pp * 325 + c8 + k] = v[k];
    }
    {   // tail channels 320..323 (CH=324)
        int pp = tid >> 2, k = tid & 3;
        int p = p0 + pp;
        size_t pix = (size_t)(p / 80 + 1) * PW + (p % 80) + 1;
        buf[pp * 325 + 320 + k] = Y[pix * CPAD + 320 + k];
    }
    __syncthreads();
    {
        int pp = tid >> 2, q = tid & 3;
        float s = 0.f, s2 = 0.f;
        for (int c = q; c < CH; c += 4) { float v = b2f(buf[pp * 325 + c]); s += v; s2 += v * v; }
        part[pp][q][0] = s; part[pp][q][1] = s2;
    }
    __syncthreads();
    if (tid < 64) {
        float s = 0.f, s2 = 0.f;
        for (int q = 0; q < 4; ++q) { s += part[tid][q][0]; s2 += part[tid][q][1]; }
        float m = s / (float)CH;
        float var = s2 / (float)CH - m * m;
        if (var < 0.f) var = 0.f;
        mean_s[tid] = m;
        inv_s[tid] = rsqrtf(var + 1e-5f);
    }
    __syncthreads();
    for (int idx = tid; idx < CH * 64; idx += 256) {
        int c = idx >> 6, pp = idx & 63;
        float v = (b2f(buf[pp * 325 + c]) - mean_s[pp]) * inv_s[pp] * g[c] + b[c];
        out[((size_t)(dir * CH + c)) * PP + p0 + pp] = v;
    }
}

extern "C" void kernel_launch(void* const* d_in, const int* in_sizes, int n_in,
                              void* d_out, int out_size, void* d_ws, size_t ws_size,
                              hipStream_t stream) {
    const float* f0  = (const float*)d_in[0];
    const float* f1  = (const float*)d_in[1];
    const float* w1  = (const float*)d_in[2];
    const float* b1  = (const float*)d_in[3];
    const float* w2  = (const float*)d_in[4];
    const float* b2  = (const float*)d_in[5];
    const float* lng = (const float*)d_in[6];
    const float* lnb = (const float*)d_in[7];
    float* out = (float*)d_out;

    char* ws = (char*)d_ws;
    size_t off = 0;
    auto alloc = [&](size_t bytes) -> char* {
        char* r = ws + off;
        off += (bytes + 511) & ~(size_t)511;
        return r;
    };
    u16* fA     = (u16*)alloc((size_t)PP * KC * 2);
    u16* fB     = (u16*)alloc((size_t)PP * KC * 2);
    u16* pc     = (u16*)alloc((size_t)2 * PP * NP2 * 2);
    u16* feat   = (u16*)alloc((size_t)2 * PPIX * CPAD * 2);
    u16* t1     = (u16*)alloc((size_t)2 * PPIX * CPAD * 2);
    u16* t2     = (u16*)alloc((size_t)2 * PPIX * CPAD * 2);
    u16* pbarA  = (u16*)alloc((size_t)2176 * KC * 2);
    u16* pbarB  = (u16*)alloc((size_t)2176 * KC * 2);
    u16* wT1    = (u16*)alloc((size_t)9 * CPAD * CPAD * 2);
    u16* wT2    = (u16*)alloc((size_t)9 * CPAD * CPAD * 2);
    float* b1p  = (float*)alloc(CPAD * 4);
    float* b2p  = (float*)alloc(CPAD * 4);

    prep_all<<<dim3(1448), 256, 0, stream>>>(f0, f1, fA, fB, w1, w2, wT1, wT2);
    zpool<<<dim3(850), 384, 0, stream>>>(feat, t1, b1, b2, b1p, b2p, fA, fB, pbarA, pbarB);
    gemm_cp<<<dim3(50, 21), 256, 0, stream>>>(fA, fB, pbarA, pbarB, pc, feat);
    lookup<<<dim3(1600, 2), 384, 0, stream>>>(pc, feat);
    conv_gemm<<<dim3(624), 256, 0, stream>>>(feat, wT1, b1p, (const u16*)0, t1);
    conv_gemm<<<dim3(624), 256, 0, stream>>>(t1, wT2, b2p, feat, t2);
    ln_out<<<dim3(100, 2), 256, 0, stream>>>(t2, lng, lnb, out);
}

// Round 12
// 237.043 us; speedup vs baseline: 1.0346x; 1.0346x over previous
//
#include <hip/hip_runtime.h>

typedef unsigned short u16;
typedef unsigned int   u32;
typedef float f32x4 __attribute__((ext_vector_type(4)));
typedef __bf16 bf16x8 __attribute__((ext_vector_type(8)));
typedef unsigned short u16x8 __attribute__((ext_vector_type(8)));
typedef unsigned short u16x4 __attribute__((ext_vector_type(4)));

#define PP   6400
#define HH   80
#define WW   80
#define KC   256
#define CH   324
#define CPAD 384
#define PW   82          // padded spatial width
#define PPIX (PW*PW)     // 6724 padded pixels
#define NP2  896         // per-m-tile pooled cols: L1 12 rows (480) + L2 12 rows (240) + L3 (100) + pad

__device__ inline float b2f(u16 u) { union { u32 i; float f; } v; v.i = ((u32)u) << 16; return v.f; }
__device__ inline u16 f2b(float f) {
    union { u32 i; float f; } v; v.f = f;
    u32 r = v.i + 0x7fffu + ((v.i >> 16) & 1u);
    return (u16)(r >> 16);
}

// async global->LDS, 16B per lane; LDS dst = wave-uniform base + lane*16
__device__ __forceinline__ void gload16(const void* g, void* l) {
    __builtin_amdgcn_global_load_lds((const __attribute__((address_space(1))) void*)g,
                                     (__attribute__((address_space(3))) void*)l, 16, 0, 0);
}

// ---------------- prep_all: feature transpose (blocks 0..799) + weight transpose (800..1447) ----------------
__global__ __launch_bounds__(256) void prep_all(const float* __restrict__ f0,
                                                const float* __restrict__ f1,
                                                u16* __restrict__ fA, u16* __restrict__ fB,
                                                const float* __restrict__ w1,
                                                const float* __restrict__ w2,
                                                u16* __restrict__ wT1, u16* __restrict__ wT2) {
    __shared__ float tile[64][65];
    int bid = (int)blockIdx.x;
    int tid = threadIdx.x;
    if (bid < 800) {
        int x = bid % 100, yb = (bid / 100) % 4, z = bid / 400;
        int p0 = x * 64, c0 = yb * 64;
        const float* src = z ? f1 : f0;
        u16* dst = z ? fB : fA;
#pragma unroll
        for (int it = 0; it < 4; ++it) {
            int idx = tid + it * 256;                 // 0..1023
            int cc = idx >> 4, pp4 = (idx & 15) * 4;
            f32x4 v = *(const f32x4*)(&src[(size_t)(c0 + cc) * PP + p0 + pp4]);
            tile[cc][pp4]     = v[0];
            tile[cc][pp4 + 1] = v[1];
            tile[cc][pp4 + 2] = v[2];
            tile[cc][pp4 + 3] = v[3];
        }
        __syncthreads();
#pragma unroll
        for (int it = 0; it < 4; ++it) {
            int idx = tid + it * 256;
            int pp = idx >> 4, cc4 = (idx & 15) * 4;
            u16x4 o;
            o[0] = f2b(tile[cc4][pp]);
            o[1] = f2b(tile[cc4 + 1][pp]);
            o[2] = f2b(tile[cc4 + 2][pp]);
            o[3] = f2b(tile[cc4 + 3][pp]);
            *(u16x4*)(&dst[(size_t)(p0 + pp) * KC + c0 + cc4]) = o;
        }
    } else {
        int b = bid - 800;
        int tap = b % 9, t6 = (b / 9) % 36, z = b / 324;
        int ci0 = (t6 / 6) * 64, co0 = (t6 % 6) * 64;
        const float* w = z ? w2 : w1;
        u16* wT = z ? wT2 : wT1;
#pragma unroll
        for (int it = 0; it < 16; ++it) {
            int idx = tid + it * 256;
            int ciL = idx >> 6, coL = idx & 63;
            int ci = ci0 + ciL, co = co0 + coL;
            tile[ciL][coL] = (ci < CH && co < CH) ? w[((size_t)tap * CH + ci) * CH + co] : 0.f;
        }
        __syncthreads();
#pragma unroll
        for (int it = 0; it < 16; ++it) {
            int idx = tid + it * 256;
            int coL = idx >> 6, ciL = idx & 63;
            wT[((size_t)tap * CPAD + co0 + coL) * CPAD + ci0 + ciL] = f2b(tile[ciL][coL]);
        }
    }
}

// ---------------- zpool: halo-zero + bias prep (blocks 0..649) + pooled features (650..849) ----------------
__global__ __launch_bounds__(384) void zpool(u16* __restrict__ feat, u16* __restrict__ t1,
                                             const float* __restrict__ b1,
                                             const float* __restrict__ b2,
                                             float* __restrict__ b1p, float* __restrict__ b2p,
                                             const u16* __restrict__ fA, const u16* __restrict__ fB,
                                             u16* __restrict__ pbarA, u16* __restrict__ pbarB) {
    int bid = (int)blockIdx.x;
    int t = threadIdx.x;
    if (bid < 650) {
        int bi = bid % 325, dir = bid / 325;
        if (bi == 324) {                              // bias-prep block
            if (dir == 0) b1p[t] = t < CH ? b1[t] : 0.f;
            else          b2p[t] = t < CH ? b2[t] : 0.f;
            return;
        }
        int pix;
        if (bi < 82) pix = bi;                        // top row
        else if (bi < 164) pix = 81 * PW + (bi - 82); // bottom row
        else if (bi < 244) pix = (bi - 164 + 1) * PW; // left col
        else pix = (bi - 244 + 1) * PW + 81;          // right col
        size_t off = ((size_t)dir * PPIX + pix) * CPAD + t;
        feat[off] = 0;
        t1[off] = 0;
        return;
    }
    if (t >= 256) return;
    int b = bid - 650;
    int j = b % 100, yy = b / 100;
    const u16* src = yy ? fA : fB;
    u16* dst = yy ? pbarA : pbarB;
    int k = t;
    int cy3 = j / 10, cx3 = j % 10;
    float l1v[16], l2v[4];
#pragma unroll
    for (int a = 0; a < 4; ++a)
#pragma unroll
        for (int bb = 0; bb < 4; ++bb) {
            int cy = cy3 * 4 + a, cx = cx3 * 4 + bb;
            int p00 = (2 * cy) * 80 + 2 * cx;
            float v = 0.25f * (b2f(src[(size_t)p00 * KC + k]) + b2f(src[(size_t)(p00 + 1) * KC + k]) +
                               b2f(src[(size_t)(p00 + 80) * KC + k]) + b2f(src[(size_t)(p00 + 81) * KC + k]));
            l1v[a * 4 + bb] = v;
            dst[(size_t)(cy * 40 + cx) * KC + k] = f2b(v);
        }
#pragma unroll
    for (int a = 0; a < 2; ++a)
#pragma unroll
        for (int bb = 0; bb < 2; ++bb) {
            float v = 0.25f * (l1v[(2 * a) * 4 + 2 * bb] + l1v[(2 * a) * 4 + 2 * bb + 1] +
                               l1v[(2 * a + 1) * 4 + 2 * bb] + l1v[(2 * a + 1) * 4 + 2 * bb + 1]);
            l2v[a * 2 + bb] = v;
            dst[(size_t)(1600 + (cy3 * 2 + a) * 20 + cx3 * 2 + bb) * KC + k] = f2b(v);
        }
    float v3 = 0.25f * (l2v[0] + l2v[1] + l2v[2] + l2v[3]);
    dst[(size_t)(2000 + j) * KC + k] = f2b(v3);
}

// ---------------- merged GEMM: banded corr (y<7) + windowed pooled-corr (y=7..20) ----------------
// R12: reverted to the R10 BK=64 form (measured best: 34KB LDS, 4 blocks/CU). Band tiles scatter
// valid L0 entries directly to feat for both directions (R8); pooled path windowed (R7).
__global__ __launch_bounds__(256) void gemm_cp(const u16* __restrict__ fA,
                                               const u16* __restrict__ fB,
                                               const u16* __restrict__ pbarA,
                                               const u16* __restrict__ pbarB,
                                               u16* __restrict__ pc,
                                               u16* __restrict__ feat) {
    int y = blockIdx.y;
    bool band = (y < 7);
    int m0 = blockIdx.x * 128, n0 = 0, jbase = 0, dir = 0;
    const u16 *Aptr, *Bptr;
    if (band) {
        int n0t = (int)blockIdx.x + y - 3;
        if (n0t < 0 || n0t >= 50) return;
        n0 = n0t * 128;
        Aptr = fA; Bptr = fB;
    } else {
        int q = y - 7;
        dir = q / 7;
        jbase = (q % 7) * 128;
        Aptr = dir ? fB : fA;
        Bptr = dir ? pbarA : pbarB;
    }
    int py0 = m0 / 80;
    int s1 = min(max(py0 / 2 - 5, 0), 28);
    int s2 = min(max(py0 / 4 - 5, 0), 8);

    __shared__ __align__(16) char smem[128 * 136 * 2];   // As+Bs (32KB) overlap trans (34KB)
    u16* As = (u16*)smem;
    u16* Bs = As + 128 * 64;
    u16* trans = (u16*)smem;
    const int TS = 136;
    int tid = threadIdx.x;
    int wave = tid >> 6, lane = tid & 63;
    int quad = lane >> 4, l16 = lane & 15;
    int lrow = lane >> 3, lchunk = lane & 7;
    int sc = lchunk ^ (lrow & 7);
    int sw = l16 & 7;
    int wr = (wave >> 1) * 64, wc = (wave & 1) * 64;
    f32x4 acc[4][4] = {};

    size_t gRow[4];
#pragma unroll
    for (int i = 0; i < 4; ++i) {
        int row = i * 32 + wave * 8 + lrow;
        if (band) gRow[i] = (size_t)(n0 + row);
        else {
            int j = jbase + row;
            int g = j < 480 ? s1 * 40 + j
                  : j < 720 ? 1120 + s2 * 20 + j
                  : j < 820 ? 1280 + j
                  : 2099;
            gRow[i] = (size_t)g;
        }
    }

    for (int k0 = 0; k0 < KC; k0 += 64) {
        __syncthreads();
#pragma unroll
        for (int i = 0; i < 4; ++i) {
            int row = i * 32 + wave * 8 + lrow;
            gload16(&Aptr[(size_t)(m0 + row) * KC + k0 + sc * 8], &As[(i * 32 + wave * 8) * 64]);
            gload16(&Bptr[gRow[i] * KC + k0 + sc * 8], &Bs[(i * 32 + wave * 8) * 64]);
        }
        __syncthreads();
#pragma unroll
        for (int ki = 0; ki < 2; ++ki) {
            bf16x8 af[4], bfr[4];
#pragma unroll
            for (int mi = 0; mi < 4; ++mi) {
                int r = wr + mi * 16 + l16;
                af[mi] = *(const bf16x8*)(&As[r * 64 + (((ki * 4 + quad) ^ sw) * 8)]);
            }
#pragma unroll
            for (int ni = 0; ni < 4; ++ni) {
                int r = wc + ni * 16 + l16;
                bfr[ni] = *(const bf16x8*)(&Bs[r * 64 + (((ki * 4 + quad) ^ sw) * 8)]);
            }
#pragma unroll
            for (int mi = 0; mi < 4; ++mi)
#pragma unroll
                for (int ni = 0; ni < 4; ++ni)
                    acc[mi][ni] = __builtin_amdgcn_mfma_f32_16x16x32_bf16(af[mi], bfr[ni], acc[mi][ni], 0, 0, 0);
        }
    }
    if (band) {
        // direct scatter of valid L0 entries to feat, both directions (R8 mapping)
        u16* fd0 = feat;
        u16* fd1 = feat + (size_t)PPIX * CPAD;
#pragma unroll
        for (int ni = 0; ni < 4; ++ni) {
            int q = n0 + wc + ni * 16 + l16;
            int qy = q / 80, qx = q - qy * 80;
            size_t qpix = (size_t)((qy + 1) * PW + qx + 1) * CPAD;
#pragma unroll
            for (int mi = 0; mi < 4; ++mi)
#pragma unroll
                for (int rr = 0; rr < 4; ++rr) {
                    int p = m0 + wr + mi * 16 + quad * 4 + rr;
                    int py = p / 80, px = p - py * 80;
                    int dx = qx - px, dy = qy - py;
                    if ((unsigned)(dx + 4) < 9u && (unsigned)(dy + 4) < 9u) {
                        u16 v = f2b(acc[mi][ni][rr]);
                        size_t ppix = (size_t)((py + 1) * PW + px + 1) * CPAD;
                        fd0[ppix + (dx + 4) * 9 + (dy + 4)] = v;
                        fd1[qpix + (4 - dx) * 9 + (4 - dy)] = v;
                    }
                }
        }
        return;
    }
    // pooled: stage tile row-major into LDS, write 256B-contiguous rows
    __syncthreads();
#pragma unroll
    for (int mi = 0; mi < 4; ++mi)
#pragma unroll
        for (int ni = 0; ni < 4; ++ni) {
            int rbase = wr + mi * 16 + quad * 4;
            int c = wc + ni * 16 + l16;
#pragma unroll
            for (int rr = 0; rr < 4; ++rr)
                trans[(rbase + rr) * TS + c] = f2b(acc[mi][ni][rr]);
        }
    __syncthreads();
#pragma unroll
    for (int it = 0; it < 8; ++it) {
        int r = it * 16 + (tid >> 4);
        int c8 = (tid & 15) * 8;
        u16x8 v = *(const u16x8*)(&trans[r * TS + c8]);
        *(u16x8*)(&pc[((size_t)dir * PP + m0 + r) * NP2 + jbase + c8]) = v;
    }
}

// ---------------- lookup: 4 pixels per block; windowed pooled rows (L1-3) + L0 zero-fill ----------------
__global__ __launch_bounds__(384) void lookup(const u16* __restrict__ pc,
                                              u16* __restrict__ feat) {
    __shared__ __align__(16) u16 pcrow[4][NP2];     // 7.2 KB
    int p0 = blockIdx.x * 4, dir = blockIdx.y;
    int tid = threadIdx.x;
    int mt = p0 >> 7;
    int py0 = (mt * 128) / 80;
    int s1 = min(max(py0 / 2 - 5, 0), 28);
    int s2 = min(max(py0 / 4 - 5, 0), 8);
    for (int i = tid; i < 4 * (NP2 / 8); i += 384) {
        int j = i / (NP2 / 8), cc = i % (NP2 / 8);
        *(u16x8*)(&pcrow[j][cc * 8]) =
            *(const u16x8*)(&pc[((size_t)dir * PP + p0 + j) * NP2 + cc * 8]);
    }
    __syncthreads();
    int ch = tid;
#pragma unroll
    for (int j = 0; j < 4; ++j) {
        int p = p0 + j;
        int px = p % WW, py = p / WW;
        size_t pix = (size_t)(py + 1) * PW + px + 1;
        if (ch < 81) {
            int dx = ch / 9 - 4, dy = ch % 9 - 4;
            int x = px + dx, yy = py + dy;
            if ((unsigned)x >= (unsigned)WW || (unsigned)yy >= (unsigned)HH)
                feat[((size_t)dir * PPIX + pix) * CPAD + ch] = 0;
            // else: already written by gemm_cp band scatter
        } else if (ch < CH) {
            int lvl = ch / 81, i = ch % 81;
            int dx = i / 9 - 4, dy = i % 9 - 4;
            int wl = WW >> lvl;
            float inv = 1.0f / (float)(2 << lvl);
            float xc = (float)(2 * px + 1) * inv - 0.5f + (float)dx;
            float yc = (float)(2 * py + 1) * inv - 0.5f + (float)dy;
            float x0f = floorf(xc), y0f = floorf(yc);
            int x0 = (int)x0f, y0 = (int)y0f;
            float wx = xc - x0f, wy = yc - y0f;
            float val = 0.f;
#pragma unroll
            for (int cy = 0; cy < 2; ++cy)
#pragma unroll
                for (int cx = 0; cx < 2; ++cx) {
                    int xi = x0 + cx, yi = y0 + cy;
                    if ((unsigned)xi < (unsigned)wl && (unsigned)yi < (unsigned)wl) {
                        float wgt = (cx ? wx : 1.f - wx) * (cy ? wy : 1.f - wy);
                        int idx = (lvl == 1) ? (yi - s1) * 40 + xi
                                : (lvl == 2) ? 480 + (yi - s2) * 20 + xi
                                             : 720 + yi * 10 + xi;
                        val += b2f(pcrow[j][idx]) * wgt;
                    }
                }
            feat[((size_t)dir * PPIX + pix) * CPAD + ch] = f2b(val);
        } else {
            feat[((size_t)dir * PPIX + pix) * CPAD + ch] = 0;
        }
    }
}

// ---------------- conv GEMM: R0/R5 proven structure (64x128 tile, BK=128, 624 blocks, ~57us) ----------------
// Structural plateau for this shape (R2/R3/R6/R9 regressed or flat): MfmaUtil pinned ~23% by
// {load-issue -> vmcnt(0) drain -> barrier -> 160cy MFMA}; any larger tile cuts grid < 2 blocks/CU.
__global__ __launch_bounds__(256) void conv_gemm(const u16* __restrict__ inFeat,
                                                 const u16* __restrict__ wTt,
                                                 const float* __restrict__ bias,
                                                 const u16* __restrict__ resid,
                                                 u16* __restrict__ outb) {
    int L = (int)blockIdx.x;
    int xcd = L & 7;
    int q = L >> 3;
    int n_t = q % 3; q /= 3;
    int mg = q % 13;
    int dir = q / 13;
    int m_t = mg * 8 + xcd;
    if (m_t >= 100) return;
    const u16* Ain = inFeat + (size_t)dir * PPIX * CPAD;
    const u16* Rin = resid ? resid + (size_t)dir * PPIX * CPAD : (const u16*)0;
    u16* Out = outb + (size_t)dir * PPIX * CPAD;
    __shared__ __align__(16) u16 As[64 * 128];    // 16KB
    __shared__ __align__(16) u16 Bs[128 * 128];   // 32KB
    int tid = threadIdx.x;
    int wave = tid >> 6, lane = tid & 63;
    int quad = lane >> 4, l16 = lane & 15;
    int wr = (wave >> 1) * 32, wc = (wave & 1) * 64;
    int m0 = m_t * 64, n0 = n_t * 128;
    f32x4 acc[2][4] = {};

    int pixA[4], scI[4];
#pragma unroll
    for (int i = 0; i < 4; ++i) {
        int r = wave * 16 + i * 4 + quad;
        int m = m0 + r;
        pixA[i] = (m / 80 + 1) * PW + (m % 80) + 1;
        scI[i] = l16 ^ ((i * 4 + quad) & 15);
    }

    for (int tap = 0; tap < 9; ++tap) {
        int dpix = (tap / 3 - 1) * PW + (tap % 3) - 1;
        const u16* Wt = wTt + ((size_t)tap * CPAD + n0) * CPAD;
#pragma unroll
        for (int kt = 0; kt < 3; ++kt) {
            int kc = kt * 128;
            __syncthreads();
#pragma unroll
            for (int i = 0; i < 4; ++i)
                gload16(&Ain[(size_t)(pixA[i] + dpix) * CPAD + kc + scI[i] * 8],
                        &As[(wave * 16 + i * 4) * 128]);
#pragma unroll
            for (int j = 0; j < 8; ++j) {
                int rb = wave * 32 + j * 4;
                gload16(&Wt[(size_t)(rb + quad) * CPAD + kc + scI[j & 3] * 8],
                        &Bs[rb * 128]);
            }
            __syncthreads();
#pragma unroll
            for (int ki = 0; ki < 4; ++ki) {
                int slot = (ki * 4 + quad) ^ l16;
                bf16x8 af[2], bfr[4];
#pragma unroll
                for (int mi = 0; mi < 2; ++mi)
                    af[mi] = *(const bf16x8*)(&As[(wr + mi * 16 + l16) * 128 + slot * 8]);
#pragma unroll
                for (int ni = 0; ni < 4; ++ni)
                    bfr[ni] = *(const bf16x8*)(&Bs[(wc + ni * 16 + l16) * 128 + slot * 8]);
#pragma unroll
                for (int mi = 0; mi < 2; ++mi)
#pragma unroll
                    for (int ni = 0; ni < 4; ++ni)
                        acc[mi][ni] = __builtin_amdgcn_mfma_f32_16x16x32_bf16(af[mi], bfr[ni], acc[mi][ni], 0, 0, 0);
            }
        }
    }
#pragma unroll
    for (int mi = 0; mi < 2; ++mi)
#pragma unroll
        for (int rr = 0; rr < 4; ++rr) {
            int p = m0 + wr + mi * 16 + quad * 4 + rr;
            size_t opix = (size_t)(p / 80 + 1) * PW + (p % 80) + 1;
#pragma unroll
            for (int ni = 0; ni < 4; ++ni) {
                int co = n0 + wc + ni * 16 + l16;
                float v = acc[mi][ni][rr] + bias[co];
                v = fmaxf(v, 0.f);
                if (Rin) v += b2f(Rin[opix * CPAD + co]);
                Out[opix * CPAD + co] = f2b(v);
            }
        }
}

// ---------------- layernorm + transposed (channel-major) output (u16x8 loads) ----------------
__global__ __launch_bounds__(256) void ln_out(const u16* __restrict__ t2,
                                              const float* __restrict__ g,
                                              const float* __restrict__ b,
                                              float* __restrict__ out) {
    int dir = blockIdx.y;
    int p0 = blockIdx.x * 64;
    const u16* Y = t2 + (size_t)dir * PPIX * CPAD;
    __shared__ u16 buf[64 * 325];
    __shared__ float mean_s[64], inv_s[64];
    __shared__ float part[64][4][2];
    int tid = threadIdx.x;
    for (int ci = tid; ci < 64 * 40; ci += 256) {
        int pp = ci / 40, c8 = (ci - pp * 40) * 8;
        int p = p0 + pp;
        size_t pix = (size_t)(p / 80 + 1) * PW + (p % 80) + 1;
        u16x8 v = *(const u16x8*)(&Y[pix * CPAD + c8]);
#pragma unroll
        for (int k = 0; k < 8; ++k) buf[pp * 325 + c8 + k] = v[k];
    }
    {   // tail channels 320..323 (CH=324)
        int pp = tid >> 2, k = tid & 3;
        int p = p0 + pp;
        size_t pix = (size_t)(p / 80 + 1) * PW + (p % 80) + 1;
        buf[pp * 325 + 320 + k] = Y[pix * CPAD + 320 + k];
    }
    __syncthreads();
    {
        int pp = tid >> 2, q = tid & 3;
        float s = 0.f, s2 = 0.f;
        for (int c = q; c < CH; c += 4) { float v = b2f(buf[pp * 325 + c]); s += v; s2 += v * v; }
        part[pp][q][0] = s; part[pp][q][1] = s2;
    }
    __syncthreads();
    if (tid < 64) {
        float s = 0.f, s2 = 0.f;
        for (int q = 0; q < 4; ++q) { s += part[tid][q][0]; s2 += part[tid][q][1]; }
        float m = s / (float)CH;
        float var = s2 / (float)CH - m * m;
        if (var < 0.f) var = 0.f;
        mean_s[tid] = m;
        inv_s[tid] = rsqrtf(var + 1e-5f);
    }
    __syncthreads();
    for (int idx = tid; idx < CH * 64; idx += 256) {
        int c = idx >> 6, pp = idx & 63;
        float v = (b2f(buf[pp * 325 + c]) - mean_s[pp]) * inv_s[pp] * g[c] + b[c];
        out[((size_t)(dir * CH + c)) * PP + p0 + pp] = v;
    }
}

extern "C" void kernel_launch(void* const* d_in, const int* in_sizes, int n_in,
                              void* d_out, int out_size, void* d_ws, size_t ws_size,
                              hipStream_t stream) {
    const float* f0  = (const float*)d_in[0];
    const float* f1  = (const float*)d_in[1];
    const float* w1  = (const float*)d_in[2];
    const float* b1  = (const float*)d_in[3];
    const float* w2  = (const float*)d_in[4];
    const float* b2  = (const float*)d_in[5];
    const float* lng = (const float*)d_in[6];
    const float* lnb = (const float*)d_in[7];
    float* out = (float*)d_out;

    char* ws = (char*)d_ws;
    size_t off = 0;
    auto alloc = [&](size_t bytes) -> char* {
        char* r = ws + off;
        off += (bytes + 511) & ~(size_t)511;
        return r;
    };
    u16* fA     = (u16*)alloc((size_t)PP * KC * 2);
    u16* fB     = (u16*)alloc((size_t)PP * KC * 2);
    u16* pc     = (u16*)alloc((size_t)2 * PP * NP2 * 2);
    u16* feat   = (u16*)alloc((size_t)2 * PPIX * CPAD * 2);
    u16* t1     = (u16*)alloc((size_t)2 * PPIX * CPAD * 2);
    u16* t2     = (u16*)alloc((size_t)2 * PPIX * CPAD * 2);
    u16* pbarA  = (u16*)alloc((size_t)2176 * KC * 2);
    u16* pbarB  = (u16*)alloc((size_t)2176 * KC * 2);
    u16* wT1    = (u16*)alloc((size_t)9 * CPAD * CPAD * 2);
    u16* wT2    = (u16*)alloc((size_t)9 * CPAD * CPAD * 2);
    float* b1p  = (float*)alloc(CPAD * 4);
    float* b2p  = (float*)alloc(CPAD * 4);

    prep_all<<<dim3(1448), 256, 0, stream>>>(f0, f1, fA, fB, w1, w2, wT1, wT2);
    zpool<<<dim3(850), 384, 0, stream>>>(feat, t1, b1, b2, b1p, b2p, fA, fB, pbarA, pbarB);
    gemm_cp<<<dim3(50, 21), 256, 0, stream>>>(fA, fB, pbarA, pbarB, pc, feat);
    lookup<<<dim3(1600, 2), 384, 0, stream>>>(pc, feat);
    conv_gemm<<<dim3(624), 256, 0, stream>>>(feat, wT1, b1p, (const u16*)0, t1);
    conv_gemm<<<dim3(624), 256, 0, stream>>>(t1, wT2, b2p, feat, t2);
    ln_out<<<dim3(100, 2), 256, 0, stream>>>(t2, lng, lnb, out);
}

// Round 13
// 235.685 us; speedup vs baseline: 1.0405x; 1.0058x over previous
//
#include <hip/hip_runtime.h>

typedef unsigned short u16;
typedef unsigned int   u32;
typedef float f32x4 __attribute__((ext_vector_type(4)));
typedef __bf16 bf16x8 __attribute__((ext_vector_type(8)));
typedef unsigned short u16x8 __attribute__((ext_vector_type(8)));
typedef unsigned short u16x4 __attribute__((ext_vector_type(4)));

#define PP   6400
#define HH   80
#define WW   80
#define KC   256
#define CH   324
#define CPAD 384
#define PW   82          // padded spatial width
#define PPIX (PW*PW)     // 6724 padded pixels
#define NP2  896         // per-m-tile pooled cols: L1 12 rows (480) + L2 12 rows (240) + L3 (100) + pad

__device__ inline float b2f(u16 u) { union { u32 i; float f; } v; v.i = ((u32)u) << 16; return v.f; }
__device__ inline u16 f2b(float f) {
    union { u32 i; float f; } v; v.f = f;
    u32 r = v.i + 0x7fffu + ((v.i >> 16) & 1u);
    return (u16)(r >> 16);
}

// async global->LDS, 16B per lane; LDS dst = wave-uniform base + lane*16
__device__ __forceinline__ void gload16(const void* g, void* l) {
    __builtin_amdgcn_global_load_lds((const __attribute__((address_space(1))) void*)g,
                                     (__attribute__((address_space(3))) void*)l, 16, 0, 0);
}

// ---------------- prep_all: feature transpose (blocks 0..799) + weight transpose (800..1447) ----------------
__global__ __launch_bounds__(256) void prep_all(const float* __restrict__ f0,
                                                const float* __restrict__ f1,
                                                u16* __restrict__ fA, u16* __restrict__ fB,
                                                const float* __restrict__ w1,
                                                const float* __restrict__ w2,
                                                u16* __restrict__ wT1, u16* __restrict__ wT2) {
    __shared__ float tile[64][65];
    int bid = (int)blockIdx.x;
    int tid = threadIdx.x;
    if (bid < 800) {
        int x = bid % 100, yb = (bid / 100) % 4, z = bid / 400;
        int p0 = x * 64, c0 = yb * 64;
        const float* src = z ? f1 : f0;
        u16* dst = z ? fB : fA;
#pragma unroll
        for (int it = 0; it < 4; ++it) {
            int idx = tid + it * 256;                 // 0..1023
            int cc = idx >> 4, pp4 = (idx & 15) * 4;
            f32x4 v = *(const f32x4*)(&src[(size_t)(c0 + cc) * PP + p0 + pp4]);
            tile[cc][pp4]     = v[0];
            tile[cc][pp4 + 1] = v[1];
            tile[cc][pp4 + 2] = v[2];
            tile[cc][pp4 + 3] = v[3];
        }
        __syncthreads();
#pragma unroll
        for (int it = 0; it < 4; ++it) {
            int idx = tid + it * 256;
            int pp = idx >> 4, cc4 = (idx & 15) * 4;
            u16x4 o;
            o[0] = f2b(tile[cc4][pp]);
            o[1] = f2b(tile[cc4 + 1][pp]);
            o[2] = f2b(tile[cc4 + 2][pp]);
            o[3] = f2b(tile[cc4 + 3][pp]);
            *(u16x4*)(&dst[(size_t)(p0 + pp) * KC + c0 + cc4]) = o;
        }
    } else {
        int b = bid - 800;
        int tap = b % 9, t6 = (b / 9) % 36, z = b / 324;
        int ci0 = (t6 / 6) * 64, co0 = (t6 % 6) * 64;
        const float* w = z ? w2 : w1;
        u16* wT = z ? wT2 : wT1;
#pragma unroll
        for (int it = 0; it < 16; ++it) {
            int idx = tid + it * 256;
            int ciL = idx >> 6, coL = idx & 63;
            int ci = ci0 + ciL, co = co0 + coL;
            tile[ciL][coL] = (ci < CH && co < CH) ? w[((size_t)tap * CH + ci) * CH + co] : 0.f;
        }
        __syncthreads();
#pragma unroll
        for (int it = 0; it < 16; ++it) {
            int idx = tid + it * 256;
            int coL = idx >> 6, ciL = idx & 63;
            wT[((size_t)tap * CPAD + co0 + coL) * CPAD + ci0 + ciL] = f2b(tile[ciL][coL]);
        }
    }
}

// ---------------- zpool: halo-zero + bias prep (blocks 0..649) + pooled features (650..849) ----------------
__global__ __launch_bounds__(384) void zpool(u16* __restrict__ feat, u16* __restrict__ t1,
                                             const float* __restrict__ b1,
                                             const float* __restrict__ b2,
                                             float* __restrict__ b1p, float* __restrict__ b2p,
                                             const u16* __restrict__ fA, const u16* __restrict__ fB,
                                             u16* __restrict__ pbarA, u16* __restrict__ pbarB) {
    int bid = (int)blockIdx.x;
    int t = threadIdx.x;
    if (bid < 650) {
        int bi = bid % 325, dir = bid / 325;
        if (bi == 324) {                              // bias-prep block
            if (dir == 0) b1p[t] = t < CH ? b1[t] : 0.f;
            else          b2p[t] = t < CH ? b2[t] : 0.f;
            return;
        }
        int pix;
        if (bi < 82) pix = bi;                        // top row
        else if (bi < 164) pix = 81 * PW + (bi - 82); // bottom row
        else if (bi < 244) pix = (bi - 164 + 1) * PW; // left col
        else pix = (bi - 244 + 1) * PW + 81;          // right col
        size_t off = ((size_t)dir * PPIX + pix) * CPAD + t;
        feat[off] = 0;
        t1[off] = 0;
        return;
    }
    if (t >= 256) return;
    int b = bid - 650;
    int j = b % 100, yy = b / 100;
    const u16* src = yy ? fA : fB;
    u16* dst = yy ? pbarA : pbarB;
    int k = t;
    int cy3 = j / 10, cx3 = j % 10;
    float l1v[16], l2v[4];
#pragma unroll
    for (int a = 0; a < 4; ++a)
#pragma unroll
        for (int bb = 0; bb < 4; ++bb) {
            int cy = cy3 * 4 + a, cx = cx3 * 4 + bb;
            int p00 = (2 * cy) * 80 + 2 * cx;
            float v = 0.25f * (b2f(src[(size_t)p00 * KC + k]) + b2f(src[(size_t)(p00 + 1) * KC + k]) +
                               b2f(src[(size_t)(p00 + 80) * KC + k]) + b2f(src[(size_t)(p00 + 81) * KC + k]));
            l1v[a * 4 + bb] = v;
            dst[(size_t)(cy * 40 + cx) * KC + k] = f2b(v);
        }
#pragma unroll
    for (int a = 0; a < 2; ++a)
#pragma unroll
        for (int bb = 0; bb < 2; ++bb) {
            float v = 0.25f * (l1v[(2 * a) * 4 + 2 * bb] + l1v[(2 * a) * 4 + 2 * bb + 1] +
                               l1v[(2 * a + 1) * 4 + 2 * bb] + l1v[(2 * a + 1) * 4 + 2 * bb + 1]);
            l2v[a * 2 + bb] = v;
            dst[(size_t)(1600 + (cy3 * 2 + a) * 20 + cx3 * 2 + bb) * KC + k] = f2b(v);
        }
    float v3 = 0.25f * (l2v[0] + l2v[1] + l2v[2] + l2v[3]);
    dst[(size_t)(2000 + j) * KC + k] = f2b(v3);
}

// ---------------- merged GEMM: banded corr (y<7) + windowed pooled-corr (y=7..20) ----------------
// BK=64 (measured best: 34KB LDS, 4 blocks/CU). Band tiles scatter valid L0 entries directly
// to feat for both directions (R8); pooled path windowed (R7); outputs 256B-coalesced (R5).
__global__ __launch_bounds__(256) void gemm_cp(const u16* __restrict__ fA,
                                               const u16* __restrict__ fB,
                                               const u16* __restrict__ pbarA,
                                               const u16* __restrict__ pbarB,
                                               u16* __restrict__ pc,
                                               u16* __restrict__ feat) {
    int y = blockIdx.y;
    bool band = (y < 7);
    int m0 = blockIdx.x * 128, n0 = 0, jbase = 0, dir = 0;
    const u16 *Aptr, *Bptr;
    if (band) {
        int n0t = (int)blockIdx.x + y - 3;
        if (n0t < 0 || n0t >= 50) return;
        n0 = n0t * 128;
        Aptr = fA; Bptr = fB;
    } else {
        int q = y - 7;
        dir = q / 7;
        jbase = (q % 7) * 128;
        Aptr = dir ? fB : fA;
        Bptr = dir ? pbarA : pbarB;
    }
    int py0 = m0 / 80;
    int s1 = min(max(py0 / 2 - 5, 0), 28);
    int s2 = min(max(py0 / 4 - 5, 0), 8);

    __shared__ __align__(16) char smem[128 * 136 * 2];   // As+Bs (32KB) overlap trans (34KB)
    u16* As = (u16*)smem;
    u16* Bs = As + 128 * 64;
    u16* trans = (u16*)smem;
    const int TS = 136;
    int tid = threadIdx.x;
    int wave = tid >> 6, lane = tid & 63;
    int quad = lane >> 4, l16 = lane & 15;
    int lrow = lane >> 3, lchunk = lane & 7;
    int sc = lchunk ^ (lrow & 7);
    int sw = l16 & 7;
    int wr = (wave >> 1) * 64, wc = (wave & 1) * 64;
    f32x4 acc[4][4] = {};

    size_t gRow[4];
#pragma unroll
    for (int i = 0; i < 4; ++i) {
        int row = i * 32 + wave * 8 + lrow;
        if (band) gRow[i] = (size_t)(n0 + row);
        else {
            int j = jbase + row;
            int g = j < 480 ? s1 * 40 + j
                  : j < 720 ? 1120 + s2 * 20 + j
                  : j < 820 ? 1280 + j
                  : 2099;
            gRow[i] = (size_t)g;
        }
    }

    for (int k0 = 0; k0 < KC; k0 += 64) {
        __syncthreads();
#pragma unroll
        for (int i = 0; i < 4; ++i) {
            int row = i * 32 + wave * 8 + lrow;
            gload16(&Aptr[(size_t)(m0 + row) * KC + k0 + sc * 8], &As[(i * 32 + wave * 8) * 64]);
            gload16(&Bptr[gRow[i] * KC + k0 + sc * 8], &Bs[(i * 32 + wave * 8) * 64]);
        }
        __syncthreads();
#pragma unroll
        for (int ki = 0; ki < 2; ++ki) {
            bf16x8 af[4], bfr[4];
#pragma unroll
            for (int mi = 0; mi < 4; ++mi) {
                int r = wr + mi * 16 + l16;
                af[mi] = *(const bf16x8*)(&As[r * 64 + (((ki * 4 + quad) ^ sw) * 8)]);
            }
#pragma unroll
            for (int ni = 0; ni < 4; ++ni) {
                int r = wc + ni * 16 + l16;
                bfr[ni] = *(const bf16x8*)(&Bs[r * 64 + (((ki * 4 + quad) ^ sw) * 8)]);
            }
#pragma unroll
            for (int mi = 0; mi < 4; ++mi)
#pragma unroll
                for (int ni = 0; ni < 4; ++ni)
                    acc[mi][ni] = __builtin_amdgcn_mfma_f32_16x16x32_bf16(af[mi], bfr[ni], acc[mi][ni], 0, 0, 0);
        }
    }
    if (band) {
        // direct scatter of valid L0 entries to feat, both directions (R8 mapping)
        u16* fd0 = feat;
        u16* fd1 = feat + (size_t)PPIX * CPAD;
#pragma unroll
        for (int ni = 0; ni < 4; ++ni) {
            int q = n0 + wc + ni * 16 + l16;
            int qy = q / 80, qx = q - qy * 80;
            size_t qpix = (size_t)((qy + 1) * PW + qx + 1) * CPAD;
#pragma unroll
            for (int mi = 0; mi < 4; ++mi)
#pragma unroll
                for (int rr = 0; rr < 4; ++rr) {
                    int p = m0 + wr + mi * 16 + quad * 4 + rr;
                    int py = p / 80, px = p - py * 80;
                    int dx = qx - px, dy = qy - py;
                    if ((unsigned)(dx + 4) < 9u && (unsigned)(dy + 4) < 9u) {
                        u16 v = f2b(acc[mi][ni][rr]);
                        size_t ppix = (size_t)((py + 1) * PW + px + 1) * CPAD;
                        fd0[ppix + (dx + 4) * 9 + (dy + 4)] = v;
                        fd1[qpix + (4 - dx) * 9 + (4 - dy)] = v;
                    }
                }
        }
        return;
    }
    // pooled: stage tile row-major into LDS, write 256B-contiguous rows
    __syncthreads();
#pragma unroll
    for (int mi = 0; mi < 4; ++mi)
#pragma unroll
        for (int ni = 0; ni < 4; ++ni) {
            int rbase = wr + mi * 16 + quad * 4;
            int c = wc + ni * 16 + l16;
#pragma unroll
            for (int rr = 0; rr < 4; ++rr)
                trans[(rbase + rr) * TS + c] = f2b(acc[mi][ni][rr]);
        }
    __syncthreads();
#pragma unroll
    for (int it = 0; it < 8; ++it) {
        int r = it * 16 + (tid >> 4);
        int c8 = (tid & 15) * 8;
        u16x8 v = *(const u16x8*)(&trans[r * TS + c8]);
        *(u16x8*)(&pc[((size_t)dir * PP + m0 + r) * NP2 + jbase + c8]) = v;
    }
}

// ---------------- lookup: 4 pixels per block; windowed pooled rows (L1-3) + L0 zero-fill ----------------
__global__ __launch_bounds__(384) void lookup(const u16* __restrict__ pc,
                                              u16* __restrict__ feat) {
    __shared__ __align__(16) u16 pcrow[4][NP2];     // 7.2 KB
    int p0 = blockIdx.x * 4, dir = blockIdx.y;
    int tid = threadIdx.x;
    int mt = p0 >> 7;
    int py0 = (mt * 128) / 80;
    int s1 = min(max(py0 / 2 - 5, 0), 28);
    int s2 = min(max(py0 / 4 - 5, 0), 8);
    for (int i = tid; i < 4 * (NP2 / 8); i += 384) {
        int j = i / (NP2 / 8), cc = i % (NP2 / 8);
        *(u16x8*)(&pcrow[j][cc * 8]) =
            *(const u16x8*)(&pc[((size_t)dir * PP + p0 + j) * NP2 + cc * 8]);
    }
    __syncthreads();
    int ch = tid;
#pragma unroll
    for (int j = 0; j < 4; ++j) {
        int p = p0 + j;
        int px = p % WW, py = p / WW;
        size_t pix = (size_t)(py + 1) * PW + px + 1;
        if (ch < 81) {
            int dx = ch / 9 - 4, dy = ch % 9 - 4;
            int x = px + dx, yy = py + dy;
            if ((unsigned)x >= (unsigned)WW || (unsigned)yy >= (unsigned)HH)
                feat[((size_t)dir * PPIX + pix) * CPAD + ch] = 0;
            // else: already written by gemm_cp band scatter
        } else if (ch < CH) {
            int lvl = ch / 81, i = ch % 81;
            int dx = i / 9 - 4, dy = i % 9 - 4;
            int wl = WW >> lvl;
            float inv = 1.0f / (float)(2 << lvl);
            float xc = (float)(2 * px + 1) * inv - 0.5f + (float)dx;
            float yc = (float)(2 * py + 1) * inv - 0.5f + (float)dy;
            float x0f = floorf(xc), y0f = floorf(yc);
            int x0 = (int)x0f, y0 = (int)y0f;
            float wx = xc - x0f, wy = yc - y0f;
            float val = 0.f;
#pragma unroll
            for (int cy = 0; cy < 2; ++cy)
#pragma unroll
                for (int cx = 0; cx < 2; ++cx) {
                    int xi = x0 + cx, yi = y0 + cy;
                    if ((unsigned)xi < (unsigned)wl && (unsigned)yi < (unsigned)wl) {
                        float wgt = (cx ? wx : 1.f - wx) * (cy ? wy : 1.f - wy);
                        int idx = (lvl == 1) ? (yi - s1) * 40 + xi
                                : (lvl == 2) ? 480 + (yi - s2) * 20 + xi
                                             : 720 + yi * 10 + xi;
                        val += b2f(pcrow[j][idx]) * wgt;
                    }
                }
            feat[((size_t)dir * PPIX + pix) * CPAD + ch] = f2b(val);
        } else {
            feat[((size_t)dir * PPIX + pix) * CPAD + ch] = 0;
        }
    }
}

// ---------------- conv GEMM: R0 K-loop (bracketed optimum) + R13 LDS-staged vectorized epilogue ----------------
// K-loop structurally plateau'd (R2/R3/R6/R9). Epilogue: stage relu(acc+bias) in f32 LDS (exact
// numerics preserved), then u16x8 resid-load + u16x8 store in 256B-contiguous rows.
__global__ __launch_bounds__(256) void conv_gemm(const u16* __restrict__ inFeat,
                                                 const u16* __restrict__ wTt,
                                                 const float* __restrict__ bias,
                                                 const u16* __restrict__ resid,
                                                 u16* __restrict__ outb) {
    int L = (int)blockIdx.x;
    int xcd = L & 7;
    int q = L >> 3;
    int n_t = q % 3; q /= 3;
    int mg = q % 13;
    int dir = q / 13;
    int m_t = mg * 8 + xcd;
    if (m_t >= 100) return;
    const u16* Ain = inFeat + (size_t)dir * PPIX * CPAD;
    const u16* Rin = resid ? resid + (size_t)dir * PPIX * CPAD : (const u16*)0;
    u16* Out = outb + (size_t)dir * PPIX * CPAD;
    __shared__ __align__(16) char smem[49152];     // As(16K)+Bs(32K); f32 trans(33.8K) overlaps
    u16* As = (u16*)smem;
    u16* Bs = As + 64 * 128;
    float* transf = (float*)smem;
    const int TSF = 132;
    int tid = threadIdx.x;
    int wave = tid >> 6, lane = tid & 63;
    int quad = lane >> 4, l16 = lane & 15;
    int wr = (wave >> 1) * 32, wc = (wave & 1) * 64;
    int m0 = m_t * 64, n0 = n_t * 128;
    f32x4 acc[2][4] = {};

    int pixA[4], scI[4];
#pragma unroll
    for (int i = 0; i < 4; ++i) {
        int r = wave * 16 + i * 4 + quad;
        int m = m0 + r;
        pixA[i] = (m / 80 + 1) * PW + (m % 80) + 1;
        scI[i] = l16 ^ ((i * 4 + quad) & 15);
    }

    for (int tap = 0; tap < 9; ++tap) {
        int dpix = (tap / 3 - 1) * PW + (tap % 3) - 1;
        const u16* Wt = wTt + ((size_t)tap * CPAD + n0) * CPAD;
#pragma unroll
        for (int kt = 0; kt < 3; ++kt) {
            int kc = kt * 128;
            __syncthreads();
#pragma unroll
            for (int i = 0; i < 4; ++i)
                gload16(&Ain[(size_t)(pixA[i] + dpix) * CPAD + kc + scI[i] * 8],
                        &As[(wave * 16 + i * 4) * 128]);
#pragma unroll
            for (int j = 0; j < 8; ++j) {
                int rb = wave * 32 + j * 4;
                gload16(&Wt[(size_t)(rb + quad) * CPAD + kc + scI[j & 3] * 8],
                        &Bs[rb * 128]);
            }
            __syncthreads();
#pragma unroll
            for (int ki = 0; ki < 4; ++ki) {
                int slot = (ki * 4 + quad) ^ l16;
                bf16x8 af[2], bfr[4];
#pragma unroll
                for (int mi = 0; mi < 2; ++mi)
                    af[mi] = *(const bf16x8*)(&As[(wr + mi * 16 + l16) * 128 + slot * 8]);
#pragma unroll
                for (int ni = 0; ni < 4; ++ni)
                    bfr[ni] = *(const bf16x8*)(&Bs[(wc + ni * 16 + l16) * 128 + slot * 8]);
#pragma unroll
                for (int mi = 0; mi < 2; ++mi)
#pragma unroll
                    for (int ni = 0; ni < 4; ++ni)
                        acc[mi][ni] = __builtin_amdgcn_mfma_f32_16x16x32_bf16(af[mi], bfr[ni], acc[mi][ni], 0, 0, 0);
            }
        }
    }
    // epilogue: stage relu(acc+bias) f32 into LDS (2-way banks, free), then coalesced writes
    __syncthreads();
#pragma unroll
    for (int mi = 0; mi < 2; ++mi)
#pragma unroll
        for (int ni = 0; ni < 4; ++ni) {
            int c = wc + ni * 16 + l16;
            float bs = bias[n0 + c];
#pragma unroll
            for (int rr = 0; rr < 4; ++rr) {
                int r = wr + mi * 16 + quad * 4 + rr;
                transf[r * TSF + c] = fmaxf(acc[mi][ni][rr] + bs, 0.f);
            }
        }
    __syncthreads();
#pragma unroll
    for (int it = 0; it < 4; ++it) {
        int r = it * 16 + (tid >> 4);
        int c8 = (tid & 15) * 8;
        int p = m0 + r;
        size_t opix = (size_t)(p / 80 + 1) * PW + (p % 80) + 1;
        u16x8 ov;
        if (Rin) {
            u16x8 rv = *(const u16x8*)(&Rin[opix * CPAD + n0 + c8]);
#pragma unroll
            for (int k = 0; k < 8; ++k) ov[k] = f2b(transf[r * TSF + c8 + k] + b2f(rv[k]));
        } else {
#pragma unroll
            for (int k = 0; k < 8; ++k) ov[k] = f2b(transf[r * TSF + c8 + k]);
        }
        *(u16x8*)(&Out[opix * CPAD + n0 + c8]) = ov;
    }
}

// ---------------- layernorm + transposed (channel-major) output (u16x8 loads) ----------------
__global__ __launch_bounds__(256) void ln_out(const u16* __restrict__ t2,
                                              const float* __restrict__ g,
                                              const float* __restrict__ b,
                                              float* __restrict__ out) {
    int dir = blockIdx.y;
    int p0 = blockIdx.x * 64;
    const u16* Y = t2 + (size_t)dir * PPIX * CPAD;
    __shared__ u16 buf[64 * 325];
    __shared__ float mean_s[64], inv_s[64];
    __shared__ float part[64][4][2];
    int tid = threadIdx.x;
    for (int ci = tid; ci < 64 * 40; ci += 256) {
        int pp = ci / 40, c8 = (ci - pp * 40) * 8;
        int p = p0 + pp;
        size_t pix = (size_t)(p / 80 + 1) * PW + (p % 80) + 1;
        u16x8 v = *(const u16x8*)(&Y[pix * CPAD + c8]);
#pragma unroll
        for (int k = 0; k < 8; ++k) buf[pp * 325 + c8 + k] = v[k];
    }
    {   // tail channels 320..323 (CH=324)
        int pp = tid >> 2, k = tid & 3;
        int p = p0 + pp;
        size_t pix = (size_t)(p / 80 + 1) * PW + (p % 80) + 1;
        buf[pp * 325 + 320 + k] = Y[pix * CPAD + 320 + k];
    }
    __syncthreads();
    {
        int pp = tid >> 2, q = tid & 3;
        float s = 0.f, s2 = 0.f;
        for (int c = q; c < CH; c += 4) { float v = b2f(buf[pp * 325 + c]); s += v; s2 += v * v; }
        part[pp][q][0] = s; part[pp][q][1] = s2;
    }
    __syncthreads();
    if (tid < 64) {
        float s = 0.f, s2 = 0.f;
        for (int q = 0; q < 4; ++q) { s += part[tid][q][0]; s2 += part[tid][q][1]; }
        float m = s / (float)CH;
        float var = s2 / (float)CH - m * m;
        if (var < 0.f) var = 0.f;
        mean_s[tid] = m;
        inv_s[tid] = rsqrtf(var + 1e-5f);
    }
    __syncthreads();
    for (int idx = tid; idx < CH * 64; idx += 256) {
        int c = idx >> 6, pp = idx & 63;
        float v = (b2f(buf[pp * 325 + c]) - mean_s[pp]) * inv_s[pp] * g[c] + b[c];
        out[((size_t)(dir * CH + c)) * PP + p0 + pp] = v;
    }
}

extern "C" void kernel_launch(void* const* d_in, const int* in_sizes, int n_in,
                              void* d_out, int out_size, void* d_ws, size_t ws_size,
                              hipStream_t stream) {
    const float* f0  = (const float*)d_in[0];
    const float* f1  = (const float*)d_in[1];
    const float* w1  = (const float*)d_in[2];
    const float* b1  = (const float*)d_in[3];
    const float* w2  = (const float*)d_in[4];
    const float* b2  = (const float*)d_in[5];
    const float* lng = (const float*)d_in[6];
    const float* lnb = (const float*)d_in[7];
    float* out = (float*)d_out;

    char* ws = (char*)d_ws;
    size_t off = 0;
    auto alloc = [&](size_t bytes) -> char* {
        char* r = ws + off;
        off += (bytes + 511) & ~(size_t)511;
        return r;
    };
    u16* fA     = (u16*)alloc((size_t)PP * KC * 2);
    u16* fB     = (u16*)alloc((size_t)PP * KC * 2);
    u16* pc     = (u16*)alloc((size_t)2 * PP * NP2 * 2);
    u16* feat   = (u16*)alloc((size_t)2 * PPIX * CPAD * 2);
    u16* t1     = (u16*)alloc((size_t)2 * PPIX * CPAD * 2);
    u16* t2     = (u16*)alloc((size_t)2 * PPIX * CPAD * 2);
    u16* pbarA  = (u16*)alloc((size_t)2176 * KC * 2);
    u16* pbarB  = (u16*)alloc((size_t)2176 * KC * 2);
    u16* wT1    = (u16*)alloc((size_t)9 * CPAD * CPAD * 2);
    u16* wT2    = (u16*)alloc((size_t)9 * CPAD * CPAD * 2);
    float* b1p  = (float*)alloc(CPAD * 4);
    float* b2p  = (float*)alloc(CPAD * 4);

    prep_all<<<dim3(1448), 256, 0, stream>>>(f0, f1, fA, fB, w1, w2, wT1, wT2);
    zpool<<<dim3(850), 384, 0, stream>>>(feat, t1, b1, b2, b1p, b2p, fA, fB, pbarA, pbarB);
    gemm_cp<<<dim3(50, 21), 256, 0, stream>>>(fA, fB, pbarA, pbarB, pc, feat);
    lookup<<<dim3(1600, 2), 384, 0, stream>>>(pc, feat);
    conv_gemm<<<dim3(624), 256, 0, stream>>>(feat, wT1, b1p, (const u16*)0, t1);
    conv_gemm<<<dim3(624), 256, 0, stream>>>(t1, wT2, b2p, feat, t2);
    ln_out<<<dim3(100, 2), 256, 0, stream>>>(t2, lng, lnb, out);
}

// Round 14
// 233.190 us; speedup vs baseline: 1.0517x; 1.0107x over previous
//
#include <hip/hip_runtime.h>

typedef unsigned short u16;
typedef unsigned int   u32;
typedef float f32x4 __attribute__((ext_vector_type(4)));
typedef __bf16 bf16x8 __attribute__((ext_vector_type(8)));
typedef unsigned short u16x8 __attribute__((ext_vector_type(8)));
typedef unsigned short u16x4 __attribute__((ext_vector_type(4)));

#define PP   6400
#define HH   80
#define WW   80
#define KC   256
#define CH   324
#define CPAD 384
#define PW   82          // padded spatial width
#define PPIX (PW*PW)     // 6724 padded pixels
#define NP2  896         // per-m-tile pooled cols: L1 12 rows (480) + L2 12 rows (240) + L3 (100) + pad

__device__ inline float b2f(u16 u) { union { u32 i; float f; } v; v.i = ((u32)u) << 16; return v.f; }
__device__ inline u16 f2b(float f) {
    union { u32 i; float f; } v; v.f = f;
    u32 r = v.i + 0x7fffu + ((v.i >> 16) & 1u);
    return (u16)(r >> 16);
}

// async global->LDS, 16B per lane; LDS dst = wave-uniform base + lane*16
__device__ __forceinline__ void gload16(const void* g, void* l) {
    __builtin_amdgcn_global_load_lds((const __attribute__((address_space(1))) void*)g,
                                     (__attribute__((address_space(3))) void*)l, 16, 0, 0);
}

// ---------------- prep_all: feature transpose (blocks 0..799) + weight transpose (800..1447) ----------------
// R14: both write phases u16x8 (16B/lane); LDS column reads are 2-way banked (free).
__global__ __launch_bounds__(256) void prep_all(const float* __restrict__ f0,
                                                const float* __restrict__ f1,
                                                u16* __restrict__ fA, u16* __restrict__ fB,
                                                const float* __restrict__ w1,
                                                const float* __restrict__ w2,
                                                u16* __restrict__ wT1, u16* __restrict__ wT2) {
    __shared__ float tile[64][65];
    int bid = (int)blockIdx.x;
    int tid = threadIdx.x;
    if (bid < 800) {
        int x = bid % 100, yb = (bid / 100) % 4, z = bid / 400;
        int p0 = x * 64, c0 = yb * 64;
        const float* src = z ? f1 : f0;
        u16* dst = z ? fB : fA;
#pragma unroll
        for (int it = 0; it < 4; ++it) {
            int idx = tid + it * 256;                 // 0..1023
            int cc = idx >> 4, pp4 = (idx & 15) * 4;
            f32x4 v = *(const f32x4*)(&src[(size_t)(c0 + cc) * PP + p0 + pp4]);
            tile[cc][pp4]     = v[0];
            tile[cc][pp4 + 1] = v[1];
            tile[cc][pp4 + 2] = v[2];
            tile[cc][pp4 + 3] = v[3];
        }
        __syncthreads();
#pragma unroll
        for (int it = 0; it < 2; ++it) {
            int idx = tid + it * 256;                 // 0..511
            int pp = idx >> 3, cc8 = (idx & 7) * 8;
            u16x8 o;
#pragma unroll
            for (int k = 0; k < 8; ++k) o[k] = f2b(tile[cc8 + k][pp]);
            *(u16x8*)(&dst[(size_t)(p0 + pp) * KC + c0 + cc8]) = o;
        }
    } else {
        int b = bid - 800;
        int tap = b % 9, t6 = (b / 9) % 36, z = b / 324;
        int ci0 = (t6 / 6) * 64, co0 = (t6 % 6) * 64;
        const float* w = z ? w2 : w1;
        u16* wT = z ? wT2 : wT1;
#pragma unroll
        for (int it = 0; it < 16; ++it) {
            int idx = tid + it * 256;
            int ciL = idx >> 6, coL = idx & 63;
            int ci = ci0 + ciL, co = co0 + coL;
            tile[ciL][coL] = (ci < CH && co < CH) ? w[((size_t)tap * CH + ci) * CH + co] : 0.f;
        }
        __syncthreads();
#pragma unroll
        for (int it = 0; it < 2; ++it) {
            int idx = tid + it * 256;                 // 0..511
            int coL = idx >> 3, ci8 = (idx & 7) * 8;
            u16x8 o;
#pragma unroll
            for (int k = 0; k < 8; ++k) o[k] = f2b(tile[ci8 + k][coL]);
            *(u16x8*)(&wT[((size_t)tap * CPAD + co0 + coL) * CPAD + ci0 + ci8]) = o;
        }
    }
}

// ---------------- zpool: halo-zero + bias prep (blocks 0..649) + pooled features (650..849) ----------------
__global__ __launch_bounds__(384) void zpool(u16* __restrict__ feat, u16* __restrict__ t1,
                                             const float* __restrict__ b1,
                                             const float* __restrict__ b2,
                                             float* __restrict__ b1p, float* __restrict__ b2p,
                                             const u16* __restrict__ fA, const u16* __restrict__ fB,
                                             u16* __restrict__ pbarA, u16* __restrict__ pbarB) {
    int bid = (int)blockIdx.x;
    int t = threadIdx.x;
    if (bid < 650) {
        int bi = bid % 325, dir = bid / 325;
        if (bi == 324) {                              // bias-prep block
            if (dir == 0) b1p[t] = t < CH ? b1[t] : 0.f;
            else          b2p[t] = t < CH ? b2[t] : 0.f;
            return;
        }
        int pix;
        if (bi < 82) pix = bi;                        // top row
        else if (bi < 164) pix = 81 * PW + (bi - 82); // bottom row
        else if (bi < 244) pix = (bi - 164 + 1) * PW; // left col
        else pix = (bi - 244 + 1) * PW + 81;          // right col
        size_t off = ((size_t)dir * PPIX + pix) * CPAD + t;
        feat[off] = 0;
        t1[off] = 0;
        return;
    }
    if (t >= 256) return;
    int b = bid - 650;
    int j = b % 100, yy = b / 100;
    const u16* src = yy ? fA : fB;
    u16* dst = yy ? pbarA : pbarB;
    int k = t;
    int cy3 = j / 10, cx3 = j % 10;
    float l1v[16], l2v[4];
#pragma unroll
    for (int a = 0; a < 4; ++a)
#pragma unroll
        for (int bb = 0; bb < 4; ++bb) {
            int cy = cy3 * 4 + a, cx = cx3 * 4 + bb;
            int p00 = (2 * cy) * 80 + 2 * cx;
            float v = 0.25f * (b2f(src[(size_t)p00 * KC + k]) + b2f(src[(size_t)(p00 + 1) * KC + k]) +
                               b2f(src[(size_t)(p00 + 80) * KC + k]) + b2f(src[(size_t)(p00 + 81) * KC + k]));
            l1v[a * 4 + bb] = v;
            dst[(size_t)(cy * 40 + cx) * KC + k] = f2b(v);
        }
#pragma unroll
    for (int a = 0; a < 2; ++a)
#pragma unroll
        for (int bb = 0; bb < 2; ++bb) {
            float v = 0.25f * (l1v[(2 * a) * 4 + 2 * bb] + l1v[(2 * a) * 4 + 2 * bb + 1] +
                               l1v[(2 * a + 1) * 4 + 2 * bb] + l1v[(2 * a + 1) * 4 + 2 * bb + 1]);
            l2v[a * 2 + bb] = v;
            dst[(size_t)(1600 + (cy3 * 2 + a) * 20 + cx3 * 2 + bb) * KC + k] = f2b(v);
        }
    float v3 = 0.25f * (l2v[0] + l2v[1] + l2v[2] + l2v[3]);
    dst[(size_t)(2000 + j) * KC + k] = f2b(v3);
}

// ---------------- merged GEMM: banded corr (y<7) + windowed pooled-corr (y=7..20) ----------------
// BK=64 (measured best: 34KB LDS, 4 blocks/CU). Band tiles scatter valid L0 entries directly
// to feat for both directions (R8); pooled path windowed (R7); outputs 256B-coalesced (R5).
__global__ __launch_bounds__(256) void gemm_cp(const u16* __restrict__ fA,
                                               const u16* __restrict__ fB,
                                               const u16* __restrict__ pbarA,
                                               const u16* __restrict__ pbarB,
                                               u16* __restrict__ pc,
                                               u16* __restrict__ feat) {
    int y = blockIdx.y;
    bool band = (y < 7);
    int m0 = blockIdx.x * 128, n0 = 0, jbase = 0, dir = 0;
    const u16 *Aptr, *Bptr;
    if (band) {
        int n0t = (int)blockIdx.x + y - 3;
        if (n0t < 0 || n0t >= 50) return;
        n0 = n0t * 128;
        Aptr = fA; Bptr = fB;
    } else {
        int q = y - 7;
        dir = q / 7;
        jbase = (q % 7) * 128;
        Aptr = dir ? fB : fA;
        Bptr = dir ? pbarA : pbarB;
    }
    int py0 = m0 / 80;
    int s1 = min(max(py0 / 2 - 5, 0), 28);
    int s2 = min(max(py0 / 4 - 5, 0), 8);

    __shared__ __align__(16) char smem[128 * 136 * 2];   // As+Bs (32KB) overlap trans (34KB)
    u16* As = (u16*)smem;
    u16* Bs = As + 128 * 64;
    u16* trans = (u16*)smem;
    const int TS = 136;
    int tid = threadIdx.x;
    int wave = tid >> 6, lane = tid & 63;
    int quad = lane >> 4, l16 = lane & 15;
    int lrow = lane >> 3, lchunk = lane & 7;
    int sc = lchunk ^ (lrow & 7);
    int sw = l16 & 7;
    int wr = (wave >> 1) * 64, wc = (wave & 1) * 64;
    f32x4 acc[4][4] = {};

    size_t gRow[4];
#pragma unroll
    for (int i = 0; i < 4; ++i) {
        int row = i * 32 + wave * 8 + lrow;
        if (band) gRow[i] = (size_t)(n0 + row);
        else {
            int j = jbase + row;
            int g = j < 480 ? s1 * 40 + j
                  : j < 720 ? 1120 + s2 * 20 + j
                  : j < 820 ? 1280 + j
                  : 2099;
            gRow[i] = (size_t)g;
        }
    }

    for (int k0 = 0; k0 < KC; k0 += 64) {
        __syncthreads();
#pragma unroll
        for (int i = 0; i < 4; ++i) {
            int row = i * 32 + wave * 8 + lrow;
            gload16(&Aptr[(size_t)(m0 + row) * KC + k0 + sc * 8], &As[(i * 32 + wave * 8) * 64]);
            gload16(&Bptr[gRow[i] * KC + k0 + sc * 8], &Bs[(i * 32 + wave * 8) * 64]);
        }
        __syncthreads();
#pragma unroll
        for (int ki = 0; ki < 2; ++ki) {
            bf16x8 af[4], bfr[4];
#pragma unroll
            for (int mi = 0; mi < 4; ++mi) {
                int r = wr + mi * 16 + l16;
                af[mi] = *(const bf16x8*)(&As[r * 64 + (((ki * 4 + quad) ^ sw) * 8)]);
            }
#pragma unroll
            for (int ni = 0; ni < 4; ++ni) {
                int r = wc + ni * 16 + l16;
                bfr[ni] = *(const bf16x8*)(&Bs[r * 64 + (((ki * 4 + quad) ^ sw) * 8)]);
            }
#pragma unroll
            for (int mi = 0; mi < 4; ++mi)
#pragma unroll
                for (int ni = 0; ni < 4; ++ni)
                    acc[mi][ni] = __builtin_amdgcn_mfma_f32_16x16x32_bf16(af[mi], bfr[ni], acc[mi][ni], 0, 0, 0);
        }
    }
    if (band) {
        // direct scatter of valid L0 entries to feat, both directions (R8 mapping)
        u16* fd0 = feat;
        u16* fd1 = feat + (size_t)PPIX * CPAD;
#pragma unroll
        for (int ni = 0; ni < 4; ++ni) {
            int q = n0 + wc + ni * 16 + l16;
            int qy = q / 80, qx = q - qy * 80;
            size_t qpix = (size_t)((qy + 1) * PW + qx + 1) * CPAD;
#pragma unroll
            for (int mi = 0; mi < 4; ++mi)
#pragma unroll
                for (int rr = 0; rr < 4; ++rr) {
                    int p = m0 + wr + mi * 16 + quad * 4 + rr;
                    int py = p / 80, px = p - py * 80;
                    int dx = qx - px, dy = qy - py;
                    if ((unsigned)(dx + 4) < 9u && (unsigned)(dy + 4) < 9u) {
                        u16 v = f2b(acc[mi][ni][rr]);
                        size_t ppix = (size_t)((py + 1) * PW + px + 1) * CPAD;
                        fd0[ppix + (dx + 4) * 9 + (dy + 4)] = v;
                        fd1[qpix + (4 - dx) * 9 + (4 - dy)] = v;
                    }
                }
        }
        return;
    }
    // pooled: stage tile row-major into LDS, write 256B-contiguous rows
    __syncthreads();
#pragma unroll
    for (int mi = 0; mi < 4; ++mi)
#pragma unroll
        for (int ni = 0; ni < 4; ++ni) {
            int rbase = wr + mi * 16 + quad * 4;
            int c = wc + ni * 16 + l16;
#pragma unroll
            for (int rr = 0; rr < 4; ++rr)
                trans[(rbase + rr) * TS + c] = f2b(acc[mi][ni][rr]);
        }
    __syncthreads();
#pragma unroll
    for (int it = 0; it < 8; ++it) {
        int r = it * 16 + (tid >> 4);
        int c8 = (tid & 15) * 8;
        u16x8 v = *(const u16x8*)(&trans[r * TS + c8]);
        *(u16x8*)(&pc[((size_t)dir * PP + m0 + r) * NP2 + jbase + c8]) = v;
    }
}

// ---------------- lookup: 4 pixels per block; windowed pooled rows (L1-3) + L0 zero-fill ----------------
__global__ __launch_bounds__(384) void lookup(const u16* __restrict__ pc,
                                              u16* __restrict__ feat) {
    __shared__ __align__(16) u16 pcrow[4][NP2];     // 7.2 KB
    int p0 = blockIdx.x * 4, dir = blockIdx.y;
    int tid = threadIdx.x;
    int mt = p0 >> 7;
    int py0 = (mt * 128) / 80;
    int s1 = min(max(py0 / 2 - 5, 0), 28);
    int s2 = min(max(py0 / 4 - 5, 0), 8);
    for (int i = tid; i < 4 * (NP2 / 8); i += 384) {
        int j = i / (NP2 / 8), cc = i % (NP2 / 8);
        *(u16x8*)(&pcrow[j][cc * 8]) =
            *(const u16x8*)(&pc[((size_t)dir * PP + p0 + j) * NP2 + cc * 8]);
    }
    __syncthreads();
    int ch = tid;
#pragma unroll
    for (int j = 0; j < 4; ++j) {
        int p = p0 + j;
        int px = p % WW, py = p / WW;
        size_t pix = (size_t)(py + 1) * PW + px + 1;
        if (ch < 81) {
            int dx = ch / 9 - 4, dy = ch % 9 - 4;
            int x = px + dx, yy = py + dy;
            if ((unsigned)x >= (unsigned)WW || (unsigned)yy >= (unsigned)HH)
                feat[((size_t)dir * PPIX + pix) * CPAD + ch] = 0;
            // else: already written by gemm_cp band scatter
        } else if (ch < CH) {
            int lvl = ch / 81, i = ch % 81;
            int dx = i / 9 - 4, dy = i % 9 - 4;
            int wl = WW >> lvl;
            float inv = 1.0f / (float)(2 << lvl);
            float xc = (float)(2 * px + 1) * inv - 0.5f + (float)dx;
            float yc = (float)(2 * py + 1) * inv - 0.5f + (float)dy;
            float x0f = floorf(xc), y0f = floorf(yc);
            int x0 = (int)x0f, y0 = (int)y0f;
            float wx = xc - x0f, wy = yc - y0f;
            float val = 0.f;
#pragma unroll
            for (int cy = 0; cy < 2; ++cy)
#pragma unroll
                for (int cx = 0; cx < 2; ++cx) {
                    int xi = x0 + cx, yi = y0 + cy;
                    if ((unsigned)xi < (unsigned)wl && (unsigned)yi < (unsigned)wl) {
                        float wgt = (cx ? wx : 1.f - wx) * (cy ? wy : 1.f - wy);
                        int idx = (lvl == 1) ? (yi - s1) * 40 + xi
                                : (lvl == 2) ? 480 + (yi - s2) * 20 + xi
                                             : 720 + yi * 10 + xi;
                        val += b2f(pcrow[j][idx]) * wgt;
                    }
                }
            feat[((size_t)dir * PPIX + pix) * CPAD + ch] = f2b(val);
        } else {
            feat[((size_t)dir * PPIX + pix) * CPAD + ch] = 0;
        }
    }
}

// ---------------- conv GEMM: R0 K-loop (bracketed optimum) + R13 LDS-staged vectorized epilogue ----------------
// K-loop structurally plateau'd (R2/R3/R6/R9). Epilogue: stage relu(acc+bias) in f32 LDS (exact
// numerics preserved), then u16x8 resid-load + u16x8 store in 256B-contiguous rows.
__global__ __launch_bounds__(256) void conv_gemm(const u16* __restrict__ inFeat,
                                                 const u16* __restrict__ wTt,
                                                 const float* __restrict__ bias,
                                                 const u16* __restrict__ resid,
                                                 u16* __restrict__ outb) {
    int L = (int)blockIdx.x;
    int xcd = L & 7;
    int q = L >> 3;
    int n_t = q % 3; q /= 3;
    int mg = q % 13;
    int dir = q / 13;
    int m_t = mg * 8 + xcd;
    if (m_t >= 100) return;
    const u16* Ain = inFeat + (size_t)dir * PPIX * CPAD;
    const u16* Rin = resid ? resid + (size_t)dir * PPIX * CPAD : (const u16*)0;
    u16* Out = outb + (size_t)dir * PPIX * CPAD;
    __shared__ __align__(16) char smem[49152];     // As(16K)+Bs(32K); f32 trans(33.8K) overlaps
    u16* As = (u16*)smem;
    u16* Bs = As + 64 * 128;
    float* transf = (float*)smem;
    const int TSF = 132;
    int tid = threadIdx.x;
    int wave = tid >> 6, lane = tid & 63;
    int quad = lane >> 4, l16 = lane & 15;
    int wr = (wave >> 1) * 32, wc = (wave & 1) * 64;
    int m0 = m_t * 64, n0 = n_t * 128;
    f32x4 acc[2][4] = {};

    int pixA[4], scI[4];
#pragma unroll
    for (int i = 0; i < 4; ++i) {
        int r = wave * 16 + i * 4 + quad;
        int m = m0 + r;
        pixA[i] = (m / 80 + 1) * PW + (m % 80) + 1;
        scI[i] = l16 ^ ((i * 4 + quad) & 15);
    }

    for (int tap = 0; tap < 9; ++tap) {
        int dpix = (tap / 3 - 1) * PW + (tap % 3) - 1;
        const u16* Wt = wTt + ((size_t)tap * CPAD + n0) * CPAD;
#pragma unroll
        for (int kt = 0; kt < 3; ++kt) {
            int kc = kt * 128;
            __syncthreads();
#pragma unroll
            for (int i = 0; i < 4; ++i)
                gload16(&Ain[(size_t)(pixA[i] + dpix) * CPAD + kc + scI[i] * 8],
                        &As[(wave * 16 + i * 4) * 128]);
#pragma unroll
            for (int j = 0; j < 8; ++j) {
                int rb = wave * 32 + j * 4;
                gload16(&Wt[(size_t)(rb + quad) * CPAD + kc + scI[j & 3] * 8],
                        &Bs[rb * 128]);
            }
            __syncthreads();
#pragma unroll
            for (int ki = 0; ki < 4; ++ki) {
                int slot = (ki * 4 + quad) ^ l16;
                bf16x8 af[2], bfr[4];
#pragma unroll
                for (int mi = 0; mi < 2; ++mi)
                    af[mi] = *(const bf16x8*)(&As[(wr + mi * 16 + l16) * 128 + slot * 8]);
#pragma unroll
                for (int ni = 0; ni < 4; ++ni)
                    bfr[ni] = *(const bf16x8*)(&Bs[(wc + ni * 16 + l16) * 128 + slot * 8]);
#pragma unroll
                for (int mi = 0; mi < 2; ++mi)
#pragma unroll
                    for (int ni = 0; ni < 4; ++ni)
                        acc[mi][ni] = __builtin_amdgcn_mfma_f32_16x16x32_bf16(af[mi], bfr[ni], acc[mi][ni], 0, 0, 0);
            }
        }
    }
    // epilogue: stage relu(acc+bias) f32 into LDS (2-way banks, free), then coalesced writes
    __syncthreads();
#pragma unroll
    for (int mi = 0; mi < 2; ++mi)
#pragma unroll
        for (int ni = 0; ni < 4; ++ni) {
            int c = wc + ni * 16 + l16;
            float bs = bias[n0 + c];
#pragma unroll
            for (int rr = 0; rr < 4; ++rr) {
                int r = wr + mi * 16 + quad * 4 + rr;
                transf[r * TSF + c] = fmaxf(acc[mi][ni][rr] + bs, 0.f);
            }
        }
    __syncthreads();
#pragma unroll
    for (int it = 0; it < 4; ++it) {
        int r = it * 16 + (tid >> 4);
        int c8 = (tid & 15) * 8;
        int p = m0 + r;
        size_t opix = (size_t)(p / 80 + 1) * PW + (p % 80) + 1;
        u16x8 ov;
        if (Rin) {
            u16x8 rv = *(const u16x8*)(&Rin[opix * CPAD + n0 + c8]);
#pragma unroll
            for (int k = 0; k < 8; ++k) ov[k] = f2b(transf[r * TSF + c8 + k] + b2f(rv[k]));
        } else {
#pragma unroll
            for (int k = 0; k < 8; ++k) ov[k] = f2b(transf[r * TSF + c8 + k]);
        }
        *(u16x8*)(&Out[opix * CPAD + n0 + c8]) = ov;
    }
}

// ---------------- layernorm + transposed (channel-major) output (u16x8 loads) ----------------
__global__ __launch_bounds__(256) void ln_out(const u16* __restrict__ t2,
                                              const float* __restrict__ g,
                                              const float* __restrict__ b,
                                              float* __restrict__ out) {
    int dir = blockIdx.y;
    int p0 = blockIdx.x * 64;
    const u16* Y = t2 + (size_t)dir * PPIX * CPAD;
    __shared__ u16 buf[64 * 325];
    __shared__ float mean_s[64], inv_s[64];
    __shared__ float part[64][4][2];
    int tid = threadIdx.x;
    for (int ci = tid; ci < 64 * 40; ci += 256) {
        int pp = ci / 40, c8 = (ci - pp * 40) * 8;
        int p = p0 + pp;
        size_t pix = (size_t)(p / 80 + 1) * PW + (p % 80) + 1;
        u16x8 v = *(const u16x8*)(&Y[pix * CPAD + c8]);
#pragma unroll
        for (int k = 0; k < 8; ++k) buf[pp * 325 + c8 + k] = v[k];
    }
    {   // tail channels 320..323 (CH=324)
        int pp = tid >> 2, k = tid & 3;
        int p = p0 + pp;
        size_t pix = (size_t)(p / 80 + 1) * PW + (p % 80) + 1;
        buf[pp * 325 + 320 + k] = Y[pix * CPAD + 320 + k];
    }
    __syncthreads();
    {
        int pp = tid >> 2, q = tid & 3;
        float s = 0.f, s2 = 0.f;
        for (int c = q; c < CH; c += 4) { float v = b2f(buf[pp * 325 + c]); s += v; s2 += v * v; }
        part[pp][q][0] = s; part[pp][q][1] = s2;
    }
    __syncthreads();
    if (tid < 64) {
        float s = 0.f, s2 = 0.f;
        for (int q = 0; q < 4; ++q) { s += part[tid][q][0]; s2 += part[tid][q][1]; }
        float m = s / (float)CH;
        float var = s2 / (float)CH - m * m;
        if (var < 0.f) var = 0.f;
        mean_s[tid] = m;
        inv_s[tid] = rsqrtf(var + 1e-5f);
    }
    __syncthreads();
    for (int idx = tid; idx < CH * 64; idx += 256) {
        int c = idx >> 6, pp = idx & 63;
        float v = (b2f(buf[pp * 325 + c]) - mean_s[pp]) * inv_s[pp] * g[c] + b[c];
        out[((size_t)(dir * CH + c)) * PP + p0 + pp] = v;
    }
}

extern "C" void kernel_launch(void* const* d_in, const int* in_sizes, int n_in,
                              void* d_out, int out_size, void* d_ws, size_t ws_size,
                              hipStream_t stream) {
    const float* f0  = (const float*)d_in[0];
    const float* f1  = (const float*)d_in[1];
    const float* w1  = (const float*)d_in[2];
    const float* b1  = (const float*)d_in[3];
    const float* w2  = (const float*)d_in[4];
    const float* b2  = (const float*)d_in[5];
    const float* lng = (const float*)d_in[6];
    const float* lnb = (const float*)d_in[7];
    float* out = (float*)d_out;

    char* ws = (char*)d_ws;
    size_t off = 0;
    auto alloc = [&](size_t bytes) -> char* {
        char* r = ws + off;
        off += (bytes + 511) & ~(size_t)511;
        return r;
    };
    u16* fA     = (u16*)alloc((size_t)PP * KC * 2);
    u16* fB     = (u16*)alloc((size_t)PP * KC * 2);
    u16* pc     = (u16*)alloc((size_t)2 * PP * NP2 * 2);
    u16* feat   = (u16*)alloc((size_t)2 * PPIX * CPAD * 2);
    u16* t1     = (u16*)alloc((size_t)2 * PPIX * CPAD * 2);
    u16* t2     = (u16*)alloc((size_t)2 * PPIX * CPAD * 2);
    u16* pbarA  = (u16*)alloc((size_t)2176 * KC * 2);
    u16* pbarB  = (u16*)alloc((size_t)2176 * KC * 2);
    u16* wT1    = (u16*)alloc((size_t)9 * CPAD * CPAD * 2);
    u16* wT2    = (u16*)alloc((size_t)9 * CPAD * CPAD * 2);
    float* b1p  = (float*)alloc(CPAD * 4);
    float* b2p  = (float*)alloc(CPAD * 4);

    prep_all<<<dim3(1448), 256, 0, stream>>>(f0, f1, fA, fB, w1, w2, wT1, wT2);
    zpool<<<dim3(850), 384, 0, stream>>>(feat, t1, b1, b2, b1p, b2p, fA, fB, pbarA, pbarB);
    gemm_cp<<<dim3(50, 21), 256, 0, stream>>>(fA, fB, pbarA, pbarB, pc, feat);
    lookup<<<dim3(1600, 2), 384, 0, stream>>>(pc, feat);
    conv_gemm<<<dim3(624), 256, 0, stream>>>(feat, wT1, b1p, (const u16*)0, t1);
    conv_gemm<<<dim3(624), 256, 0, stream>>>(t1, wT2, b2p, feat, t2);
    ln_out<<<dim3(100, 2), 256, 0, stream>>>(t2, lng, lnb, out);
}